// Round 6
// baseline (677.676 us; speedup 1.0000x reference)
//
#include <hip/hip_runtime.h>
#include <math.h>

// ---------------------------------------------------------------------------
// TannerGNN. Round 21: commute W2 past the destination sum.
//   agg[d] = sum_t [ (sum_{e: type t, dst d} relu(PT_t[src]+PB_t[d])) @ W2_t
//                    + count_t(d) * b2_t ]
// Pipeline per layer:
//   k_nodeproj: PT = hb@W1top + b1, PB = hb@W1bot  (bf16 stored, MFMA GEMM)
//   k_edge:     per (type,dst) key, ONE WAVE owns the run: gather PT[src],
//               add PB[d] (loaded once), relu, f32 accumulate, plain-store
//               HA[key]. No MFMA, no LDS, no atomics.
//   k_aggmm:    dense per-node GEMM: agg = split(HA0)@W2_0 + c0*b2_0
//               + split(HA1)@W2_1 + c1*b2_1 (hi/lo split; count-gated so
//               garbage in empty keys never enters). Plain stores -> all agg
//               zeroing deleted (k_prep, k_gru).
// Edge-level MFMA work drops 4x (400k edges -> 100k node-type rows); the edge
// kernel is pure bandwidth (bf16 P halves R20's gather bytes). R20 proved
// absmax tolerates f32 re-association (0.02734->0.02686 passed).
// k_prep/sort/k_gru/k_readout otherwise identical to R15/R16.
// N_NODES=50000, N_EDGES=400000, H=128, L=3, T=2, FEAT=4, N_DATA=40000.
// ---------------------------------------------------------------------------

#define H 128
#define HS  136        // sIn row stride in bf16 (gru/readout)
#define EXS 132        // sEx row stride in f32 (2-way banks)
#define FEAT 4
#define WG_PER_LAYER 196608   // 2 mat * 2 split * 4 kc * 24 jtg * 64 lane * 8
#define WR_TOTAL 32768        // 2 split * 4 kc * 8 jtg * 64 lane * 8
#define WC_TOTAL 294912       // 6 lt * 12 chunk * 4096

typedef __bf16 bf16x8 __attribute__((ext_vector_type(8)));
typedef __bf16 bf16x4 __attribute__((ext_vector_type(4)));
typedef __bf16 bf16x2 __attribute__((ext_vector_type(2)));
typedef float  f32x4  __attribute__((ext_vector_type(4)));

// async global->LDS, 16B per lane; l must be the wave-uniform base
// (HW writes lane i at l + i*16), g is the per-lane global address.
__device__ __forceinline__ void gload_lds16(const void* g, void* l) {
    __builtin_amdgcn_global_load_lds(
        (const __attribute__((address_space(1))) void*)g,
        (__attribute__((address_space(3))) void*)l, 16, 0, 0);
}

// ---------------- mega-prep: weight swizzles + cnt zero + input proj -------
__global__ __launch_bounds__(256) void k_prep(
    const float* __restrict__ W1, const float* __restrict__ W2,
    const float* __restrict__ Wih, const float* __restrict__ Whh,
    const float* __restrict__ Wr1,
    const float* __restrict__ x, const float* __restrict__ Win,
    const float* __restrict__ bin,
    __bf16* __restrict__ Wsw, __bf16* __restrict__ Wg,
    __bf16* __restrict__ Wr1s, int* __restrict__ cnt,
    float* __restrict__ h, __bf16* __restrict__ hb,
    int n_nodes)
{
    const int N1 = WC_TOTAL;
    const int N2 = 3 * WG_PER_LAYER;
    const int N3 = WR_TOTAL;
    const int N4 = 2 * n_nodes;
    const long long N5 = (long long)n_nodes * H;
    long long gid = (long long)blockIdx.x * 256 + threadIdx.x;

    if (gid < N1) {
        int g = (int)gid;
        const int per_lt = 12 * 4096;
        int lt = g / per_lt, rem = g % per_lt;
        int chunk = rem >> 12;
        int within = rem & 4095;
        int ct = within >> 9;
        int lane = (within >> 3) & 63;
        int j = within & 7;
        int r = lane & 15, quad = lane >> 4;
        int n = ct * 16 + r;
        float v;
        if (chunk < 8) {
            int k = chunk * 32 + quad * 8 + j;
            v = W1[((size_t)lt * 256 + k) * 128 + n];
        } else {
            int k = (chunk - 8) * 32 + quad * 8 + j;
            v = W2[((size_t)lt * 128 + k) * 128 + n];
        }
        Wsw[g] = (__bf16)v;
        return;
    }
    gid -= N1;
    if (gid < N2) {
        int g = (int)gid;
        int layer = g / WG_PER_LAYER, rem = g % WG_PER_LAYER;
        int t = rem & 7;
        int lane = (rem >> 3) & 63;
        int jtg = (rem >> 9) % 24;
        int mk = rem / 12288;          // (mat*2+split)*4 + kc
        int kc = mk & 3;
        int msplit = mk >> 2;
        int mat = msplit >> 1, split = msplit & 1;
        int r = lane & 15, quad = lane >> 4;
        int k = kc * 32 + quad * 8 + t;
        int n = jtg * 16 + r;
        const float* W = (mat ? Whh : Wih) + (size_t)layer * 128 * 384;
        float v = W[(size_t)k * 384 + n];
        __bf16 hi = (__bf16)v;
        Wg[g] = split ? (__bf16)(v - (float)hi) : hi;
        return;
    }
    gid -= N2;
    if (gid < N3) {
        int g = (int)gid;
        int t = g & 7;
        int lane = (g >> 3) & 63;
        int jtg = (g >> 9) & 7;
        int kc = (g >> 12) & 3;
        int split = g >> 14;
        int r = lane & 15, quad = lane >> 4;
        int k = kc * 32 + quad * 8 + t;
        int n = jtg * 16 + r;
        float v = Wr1[(size_t)k * H + n];
        __bf16 hi = (__bf16)v;
        Wr1s[g] = split ? (__bf16)(v - (float)hi) : hi;
        return;
    }
    gid -= N3;
    if (gid < N4) {
        cnt[(int)gid] = 0;
        return;
    }
    gid -= N4;
    if (gid < N5) {
        int idx = (int)gid;
        int n = idx >> 7, j = idx & 127;
        float acc = bin[j];
#pragma unroll
        for (int f = 0; f < FEAT; f++)
            acc += x[n * FEAT + f] * Win[f * H + j];
        float v = fmaxf(acc, 0.f);
        h[idx] = v;
        hb[idx] = (__bf16)v;
    }
}

// ---------------- counting sort by key = type*nn + dst ---------------------
__global__ __launch_bounds__(256) void k_hist(
    const int* __restrict__ et, const int* __restrict__ dst,
    int* __restrict__ cnt, int n_edges, int nn)
{
    int i = blockIdx.x * 256 + threadIdx.x;
    if (i < n_edges) atomicAdd(&cnt[et[i] * nn + dst[i]], 1);
}

__global__ __launch_bounds__(1024) void k_scan1(
    const int* __restrict__ cnt, int* __restrict__ bsum, int n)
{
    int i = blockIdx.x * 1024 + threadIdx.x;
    int v = (i < n) ? cnt[i] : 0;
#pragma unroll
    for (int off = 32; off > 0; off >>= 1) v += __shfl_down(v, off, 64);
    __shared__ int ws[16];
    int lane = threadIdx.x & 63, w = threadIdx.x >> 6;
    if (lane == 0) ws[w] = v;
    __syncthreads();
    if (threadIdx.x < 16) {
        int x = ws[threadIdx.x];
#pragma unroll
        for (int off = 8; off > 0; off >>= 1) x += __shfl_down(x, off, 64);
        if (threadIdx.x == 0) bsum[blockIdx.x] = x;
    }
}

__global__ __launch_bounds__(128) void k_scan2(
    int* __restrict__ bsum, int* __restrict__ offs, int nb, int n)
{
    int lane = threadIdx.x & 63, w = threadIdx.x >> 6;
    int v = (threadIdx.x < nb) ? bsum[threadIdx.x] : 0;
    int orig = v;
#pragma unroll
    for (int off = 1; off < 64; off <<= 1) {
        int t = __shfl_up(v, off, 64);
        if (lane >= off) v += t;
    }
    __shared__ int w0sum;
    if (threadIdx.x == 63) w0sum = v;
    __syncthreads();
    int ex = v - orig + (w ? w0sum : 0);
    if (threadIdx.x < nb) bsum[threadIdx.x] = ex;
    if (threadIdx.x == nb - 1) offs[n] = ex + orig;
}

__global__ __launch_bounds__(1024) void k_scan3(
    const int* __restrict__ cnt, const int* __restrict__ bsum,
    int* __restrict__ offs, int n)
{
    int i = blockIdx.x * 1024 + threadIdx.x;
    int v = (i < n) ? cnt[i] : 0;
    int orig = v;
    int lane = threadIdx.x & 63, w = threadIdx.x >> 6;
#pragma unroll
    for (int off = 1; off < 64; off <<= 1) {
        int t = __shfl_up(v, off, 64);
        if (lane >= off) v += t;
    }
    __shared__ int ws[16];
    if (lane == 63) ws[w] = v;
    __syncthreads();
    if (threadIdx.x < 16) {
        int x = ws[threadIdx.x];
#pragma unroll
        for (int off = 1; off < 16; off <<= 1) {
            int t = __shfl_up(x, off, 64);
            if (lane >= off) x += t;
        }
        ws[threadIdx.x] = x;
    }
    __syncthreads();
    int wbase = w ? ws[w - 1] : 0;
    if (i < n) offs[i] = bsum[blockIdx.x] + wbase + v - orig;
}

__global__ __launch_bounds__(256) void k_place(
    const int* __restrict__ et, const int* __restrict__ dst,
    const int* __restrict__ offs, int* __restrict__ cnt,
    int* __restrict__ bucket, int n_edges, int nn)
{
    int i = blockIdx.x * 256 + threadIdx.x;
    if (i < n_edges) {
        int key = et[i] * nn + dst[i];
        int p = atomicAdd(&cnt[key], -1) - 1;
        bucket[offs[key] + p] = i;
    }
}

// ---------------- per-node projections: PT = hb@W1top + b1, PB = hb@W1bot --
// Dense MFMA GEMM per (layer,type); 64 nodes/block, 4 waves x 16 nodes.
// Outputs stored bf16 (halves write + later gather traffic).
__global__ __launch_bounds__(256, 4) void k_nodeproj(
    const __bf16* __restrict__ hb, const __bf16* __restrict__ Wsw,
    const float* __restrict__ b1l,
    __bf16* __restrict__ PT, __bf16* __restrict__ PB, int n_nodes)
{
    const int t = blockIdx.y;
    const int nb = blockIdx.x * 64;
    const __bf16* __restrict__ W = Wsw + (size_t)t * 12 * 4096;
    const float*  __restrict__ b1 = b1l + t * H;

    __shared__ __bf16 sW[2][4096];

    const int tid = threadIdx.x, lane = tid & 63, w = tid >> 6;  // w: 0..3
    const int r = lane & 15, quad = lane >> 4;

    // stage chunk 0: two 4KB issues (256 thr x 16B)
    gload_lds16(W + (size_t)tid * 8, (char*)&sW[0][0] + (size_t)w * 1024);
    gload_lds16(W + 2048 + (size_t)tid * 8,
                (char*)&sW[0][0] + 4096 + (size_t)w * 1024);

    const int n = nb + w * 16 + r;
    const int nc = (n < n_nodes) ? n : (n_nodes - 1);
    const __bf16* ap = hb + (size_t)nc * H;
    bf16x8 bf[4];
#pragma unroll
    for (int kc = 0; kc < 4; kc++)
        bf[kc] = *(const bf16x8*)(ap + kc * 32 + quad * 8);

    f32x4 at[8], ab[8];
#pragma unroll
    for (int ct = 0; ct < 8; ct++) {
        at[ct] = (f32x4){0.f, 0.f, 0.f, 0.f};
        ab[ct] = (f32x4){0.f, 0.f, 0.f, 0.f};
    }

#pragma unroll
    for (int c = 0; c < 8; c++) {
        __syncthreads();
        if (c < 7) {
            gload_lds16(W + (size_t)(c + 1) * 4096 + (size_t)tid * 8,
                        (char*)&sW[(c + 1) & 1][0] + (size_t)w * 1024);
            gload_lds16(W + (size_t)(c + 1) * 4096 + 2048 + (size_t)tid * 8,
                        (char*)&sW[(c + 1) & 1][0] + 4096 + (size_t)w * 1024);
        }
        const __bf16* cw = &sW[c & 1][0];
        bf16x8 b = bf[c & 3];
        if (c < 4) {
#pragma unroll
            for (int ct = 0; ct < 8; ct++) {
                bf16x8 a = *(const bf16x8*)(cw + ct * 512 + lane * 8);
                at[ct] = __builtin_amdgcn_mfma_f32_16x16x32_bf16(a, b, at[ct], 0, 0, 0);
            }
        } else {
#pragma unroll
            for (int ct = 0; ct < 8; ct++) {
                bf16x8 a = *(const bf16x8*)(cw + ct * 512 + lane * 8);
                ab[ct] = __builtin_amdgcn_mfma_f32_16x16x32_bf16(a, b, ab[ct], 0, 0, 0);
            }
        }
    }

    if (n < n_nodes) {
        __bf16* pt = PT + ((size_t)t * n_nodes + n) * H;
        __bf16* pb = PB + ((size_t)t * n_nodes + n) * H;
#pragma unroll
        for (int ct = 0; ct < 8; ct++) {
            f32x4 bb4 = *(const f32x4*)(b1 + ct * 16 + quad * 4);
            bf16x4 vt, vb;
#pragma unroll
            for (int g4 = 0; g4 < 4; g4++) {
                vt[g4] = (__bf16)(at[ct][g4] + bb4[g4]);   // fold b1 into PT
                vb[g4] = (__bf16)(ab[ct][g4]);
            }
            *(bf16x4*)(pt + ct * 16 + quad * 4) = vt;
            *(bf16x4*)(pb + ct * 16 + quad * 4) = vb;
        }
    }
}

// ---------------- edge sum: HA[key] = sum relu(PT[src] + PB[dst]) ----------
// One wave per (type,dst) key; lane owns features 2*lane, 2*lane+1.
// PB row loaded once per key; PT rows gathered per edge; plain store (no
// atomics) -- key ownership is exclusive. Empty keys exit (count-gated later).
__global__ __launch_bounds__(512) void k_edge(
    const __bf16* __restrict__ PT, const __bf16* __restrict__ PB,
    const int* __restrict__ bucket, const int* __restrict__ offs,
    const int* __restrict__ src,
    float* __restrict__ HA, int nn)
{
    const int key = blockIdx.x * 8 + (threadIdx.x >> 6);
    if (key >= 2 * nn) return;
    const int e0 = offs[key], e1 = offs[key + 1];
    if (e0 == e1) return;
    const int lane = threadIdx.x & 63;
    const size_t tbase = (key >= nn) ? (size_t)nn : 0;   // type row base

    bf16x2 pv = *(const bf16x2*)(PB + (size_t)key * H + 2 * lane);
    const float p0 = (float)pv[0], p1 = (float)pv[1];

    float a0 = 0.f, a1 = 0.f;
    for (int e = e0; e < e1; ++e) {
        int s = src[bucket[e]];
        bf16x2 tv = *(const bf16x2*)(PT + (tbase + s) * H + 2 * lane);
        a0 += fmaxf((float)tv[0] + p0, 0.f);
        a1 += fmaxf((float)tv[1] + p1, 0.f);
    }
    float2 o; o.x = a0; o.y = a1;
    *(float2*)(HA + (size_t)key * H + 2 * lane) = o;
}

// ---------------- agg GEMM: agg = split(HA_t)@W2_t + c_t*b2_t summed -------
// 64 nodes/block, 4 waves x 16 nodes; A = Wsw W2 chunks (8..11 per type),
// B = hi/lo bf16 split of HA rows (count-gated). Plain stores to agg.
__global__ __launch_bounds__(256) void k_aggmm(
    const float* __restrict__ HA, const int* __restrict__ offs,
    const __bf16* __restrict__ Wsw, const float* __restrict__ b2l,
    float* __restrict__ agg, int nn)
{
    const int nb = blockIdx.x * 64;
    __shared__ __bf16 sW[2][4096];

    const int tid = threadIdx.x, lane = tid & 63, w = tid >> 6;  // w: 0..3
    const int r = lane & 15, quad = lane >> 4;

    // stage chunk 0 = (t=0, kc=0): W2_0 chunk 8 of type 0
    gload_lds16(Wsw + (size_t)8 * 4096 + (size_t)tid * 8,
                (char*)&sW[0][0] + (size_t)w * 1024);
    gload_lds16(Wsw + (size_t)8 * 4096 + 2048 + (size_t)tid * 8,
                (char*)&sW[0][0] + 4096 + (size_t)w * 1024);

    const int n = nb + w * 16 + r;
    const int nc = (n < nn) ? n : (nn - 1);
    const int c0 = offs[nc + 1] - offs[nc];
    const int c1 = offs[nn + nc + 1] - offs[nn + nc];

    // B frags (hi/lo) for both types, count-gated (garbage never enters)
    bf16x8 bhi[2][4], blo[2][4];
#pragma unroll
    for (int t = 0; t < 2; t++) {
        const float* ha = HA + ((size_t)t * nn + nc) * H;
        const int cT = t ? c1 : c0;
#pragma unroll
        for (int kc = 0; kc < 4; kc++) {
            f32x4 u0 = *(const f32x4*)(ha + kc * 32 + quad * 8);
            f32x4 u1 = *(const f32x4*)(ha + kc * 32 + quad * 8 + 4);
#pragma unroll
            for (int j = 0; j < 4; j++) {
                float v0 = cT ? u0[j] : 0.f;
                float v1 = cT ? u1[j] : 0.f;
                __bf16 h0 = (__bf16)v0, h1 = (__bf16)v1;
                bhi[t][kc][j] = h0;     blo[t][kc][j] = (__bf16)(v0 - (float)h0);
                bhi[t][kc][4 + j] = h1; blo[t][kc][4 + j] = (__bf16)(v1 - (float)h1);
            }
        }
    }

    f32x4 acc[8];
#pragma unroll
    for (int ct = 0; ct < 8; ct++) acc[ct] = (f32x4){0.f, 0.f, 0.f, 0.f};

    // 8 chunks: c = t*4 + kc; W2_t chunk = Wsw + (t*12 + 8 + kc)*4096
#pragma unroll
    for (int c = 0; c < 8; c++) {
        __syncthreads();
        if (c < 7) {
            int t2 = (c + 1) >> 2, k2 = (c + 1) & 3;
            size_t off = (size_t)(t2 * 12 + 8 + k2) * 4096;
            gload_lds16(Wsw + off + (size_t)tid * 8,
                        (char*)&sW[(c + 1) & 1][0] + (size_t)w * 1024);
            gload_lds16(Wsw + off + 2048 + (size_t)tid * 8,
                        (char*)&sW[(c + 1) & 1][0] + 4096 + (size_t)w * 1024);
        }
        const __bf16* cw = &sW[c & 1][0];
        const int t = c >> 2, kc = c & 3;
        bf16x8 bh = bhi[t][kc], bl = blo[t][kc];
#pragma unroll
        for (int ct = 0; ct < 8; ct++) {
            bf16x8 a = *(const bf16x8*)(cw + ct * 512 + lane * 8);
            acc[ct] = __builtin_amdgcn_mfma_f32_16x16x32_bf16(a, bh, acc[ct], 0, 0, 0);
            acc[ct] = __builtin_amdgcn_mfma_f32_16x16x32_bf16(a, bl, acc[ct], 0, 0, 0);
        }
    }

    if (n < nn) {
        float* ag = agg + (size_t)n * H;
        const float f0 = (float)c0, f1 = (float)c1;
#pragma unroll
        for (int ct = 0; ct < 8; ct++) {
            f32x4 b20 = *(const f32x4*)(b2l + ct * 16 + quad * 4);
            f32x4 b21 = *(const f32x4*)(b2l + H + ct * 16 + quad * 4);
            f32x4 ov;
#pragma unroll
            for (int g4 = 0; g4 < 4; g4++)
                ov[g4] = acc[ct][g4] + f0 * b20[g4] + f1 * b21[g4];
            *(f32x4*)(ag + ct * 16 + quad * 4) = ov;
        }
    }
}

// ---------------- GRU cell: split-precision MFMA, mat-specialized waves ----
// last=1 (final layer): skip dead hb write. (agg zeroing removed: k_aggmm
// plain-stores agg every layer.)
__global__ __launch_bounds__(1024, 4) void k_gru(
    float* __restrict__ h, __bf16* __restrict__ hb,
    const float* __restrict__ agg,
    const __bf16* __restrict__ Wg,
    const float* __restrict__ bih, const float* __restrict__ bhh,
    int n_nodes, int last)
{
    const int nb = blockIdx.x * 32;
    const int tid = threadIdx.x;

    // phase 1: sIn[4][32][HS] bf16 (34816 B); phase 2: sEx[3][32][EXS] f32
    __shared__ char sRaw[3 * 32 * EXS * 4];          // 50688 B
    __bf16 (*sIn)[32][HS] = (__bf16(*)[32][HS])sRaw;
    float* sEx = (float*)sRaw;

    {   // stage + split inputs: one float4 of agg + h per thread
        int e = tid >> 5, c4 = (tid & 31) * 4;
        int n = nb + e;
        float4 av = {0.f, 0.f, 0.f, 0.f}, hv = {0.f, 0.f, 0.f, 0.f};
        if (n < n_nodes) {
            av = *(const float4*)(agg + (size_t)n * H + c4);
            hv = *(const float4*)(h + (size_t)n * H + c4);
        }
        bf16x4 ahi, alo, hhi, hlo;
        float af[4] = {av.x, av.y, av.z, av.w};
        float hf[4] = {hv.x, hv.y, hv.z, hv.w};
#pragma unroll
        for (int c = 0; c < 4; c++) {
            __bf16 ah = (__bf16)af[c]; ahi[c] = ah; alo[c] = (__bf16)(af[c] - (float)ah);
            __bf16 hh = (__bf16)hf[c]; hhi[c] = hh; hlo[c] = (__bf16)(hf[c] - (float)hh);
        }
        *(bf16x4*)&sIn[0][e][c4] = ahi;
        *(bf16x4*)&sIn[1][e][c4] = alo;
        *(bf16x4*)&sIn[2][e][c4] = hhi;
        *(bf16x4*)&sIn[3][e][c4] = hlo;
    }
    __syncthreads();

    const int lane = tid & 63, w = tid >> 6;     // w: 0..15
    const int r = lane & 15, quad = lane >> 4;
    const int jt = w & 7;
    const int mat = w >> 3;

    f32x4 acc[2][3];                     // [m][gate]
#pragma unroll
    for (int m = 0; m < 2; m++)
#pragma unroll
        for (int g = 0; g < 3; g++)
            acc[m][g] = (f32x4){0.f, 0.f, 0.f, 0.f};

    bf16x8 B[2][6];                      // [buf][g*2+split]
#pragma unroll
    for (int g = 0; g < 3; g++)
#pragma unroll
    for (int sp = 0; sp < 2; sp++)
        B[0][g * 2 + sp] = *(const bf16x8*)(Wg +
            ((((size_t)(mat * 2 + sp) * 4 + 0) * 24 + (g * 8 + jt)) * 64 + lane) * 8);

#pragma unroll
    for (int kc = 0; kc < 4; kc++) {
        const int cur = kc & 1, nxt = cur ^ 1;
        if (kc < 3) {
#pragma unroll
            for (int g = 0; g < 3; g++)
#pragma unroll
            for (int sp = 0; sp < 2; sp++)
                B[nxt][g * 2 + sp] = *(const bf16x8*)(Wg +
                    ((((size_t)(mat * 2 + sp) * 4 + (kc + 1)) * 24 + (g * 8 + jt)) * 64 + lane) * 8);
        }
        bf16x8 A[2][2];
#pragma unroll
        for (int m = 0; m < 2; m++)
#pragma unroll
            for (int s = 0; s < 2; s++)
                A[m][s] = *(const bf16x8*)&sIn[mat * 2 + s][m * 16 + r][kc * 32 + quad * 8];
#pragma unroll
        for (int g = 0; g < 3; g++) {
            bf16x8 bhi = B[cur][g * 2 + 0];
            bf16x8 blo = B[cur][g * 2 + 1];
#pragma unroll
            for (int m = 0; m < 2; m++) {
                acc[m][g] = __builtin_amdgcn_mfma_f32_16x16x32_bf16(
                    A[m][0], bhi, acc[m][g], 0, 0, 0);
                acc[m][g] = __builtin_amdgcn_mfma_f32_16x16x32_bf16(
                    A[m][0], blo, acc[m][g], 0, 0, 0);
                acc[m][g] = __builtin_amdgcn_mfma_f32_16x16x32_bf16(
                    A[m][1], bhi, acc[m][g], 0, 0, 0);
            }
        }
    }

    __syncthreads();   // all sIn reads done before sEx overwrites

    const int jcol = jt * 16 + r;
    if (mat == 1) {    // publish recurrent-gate accs
#pragma unroll
        for (int m = 0; m < 2; m++)
#pragma unroll
        for (int g = 0; g < 3; g++)
#pragma unroll
        for (int g4 = 0; g4 < 4; g4++) {
            int e = m * 16 + quad * 4 + g4;
            sEx[(g * 32 + e) * EXS + jcol] = acc[m][g][g4];
        }
    }
    __syncthreads();

    if (mat == 0) {    // gate epilogue
        float br_ = bih[jcol], bz_ = bih[128 + jcol], bn_ = bih[256 + jcol];
        float cr = bhh[jcol], cz = bhh[128 + jcol], cn = bhh[256 + jcol];
#pragma unroll
        for (int m = 0; m < 2; m++)
#pragma unroll
        for (int g4 = 0; g4 < 4; g4++) {
            int e = m * 16 + quad * 4 + g4;
            int n = nb + e;
            if (n < n_nodes) {
                float ir = acc[m][0][g4], iz = acc[m][1][g4], in_ = acc[m][2][g4];
                float hr = sEx[(0 * 32 + e) * EXS + jcol];
                float hz = sEx[(1 * 32 + e) * EXS + jcol];
                float hn = sEx[(2 * 32 + e) * EXS + jcol];
                float hold = h[(size_t)n * H + jcol];
                float rr = 1.f / (1.f + expf(-(ir + br_ + hr + cr)));
                float zz = 1.f / (1.f + expf(-(iz + bz_ + hz + cz)));
                float nv = tanhf(in_ + bn_ + rr * (hn + cn));
                float out = (1.f - zz) * nv + zz * hold;
                h[(size_t)n * H + jcol] = out;
                if (!last) hb[(size_t)n * H + jcol] = (__bf16)out;
            }
        }
    }
}

// ---------------- readout: split-precision MFMA ----------------------------
__global__ __launch_bounds__(256, 4) void k_readout(
    const float* __restrict__ h, const __bf16* __restrict__ Wr1s,
    const float* __restrict__ br1, const float* __restrict__ Wr2,
    const float* __restrict__ br2, float* __restrict__ out, int n_out)
{
    const int nb = blockIdx.x * 32;
    const int tid = threadIdx.x;
    __shared__ __bf16 sIn[2][32][HS];   // h hi/lo (17.4 KB)
    __shared__ float sRed[4][32];

#pragma unroll
    for (int v = 0; v < 4; v++) {
        int idx = tid + 256 * v;            // float4 id, 1024 total
        int e = idx >> 5, c4 = (idx & 31) * 4;
        int n = nb + e;
        float4 hv = {0.f, 0.f, 0.f, 0.f};
        if (n < n_out)
            hv = *(const float4*)(h + (size_t)n * H + c4);
        float hf[4] = {hv.x, hv.y, hv.z, hv.w};
        bf16x4 hhi, hlo;
#pragma unroll
        for (int c = 0; c < 4; c++) {
            __bf16 hh = (__bf16)hf[c];
            hhi[c] = hh; hlo[c] = (__bf16)(hf[c] - (float)hh);
        }
        *(bf16x4*)&sIn[0][e][c4] = hhi;
        *(bf16x4*)&sIn[1][e][c4] = hlo;
    }
    __syncthreads();

    const int lane = tid & 63, w = tid >> 6;
    const int r = lane & 15, quad = lane >> 4;

    f32x4 acc[2][2];                 // [m][j]
#pragma unroll
    for (int m = 0; m < 2; m++)
#pragma unroll
        for (int j = 0; j < 2; j++)
            acc[m][j] = (f32x4){0.f, 0.f, 0.f, 0.f};

#pragma unroll
    for (int kc = 0; kc < 4; kc++) {
        bf16x8 A[2][2];
#pragma unroll
        for (int m = 0; m < 2; m++)
#pragma unroll
            for (int s = 0; s < 2; s++)
                A[m][s] = *(const bf16x8*)&sIn[s][m * 16 + r][kc * 32 + quad * 8];
#pragma unroll
        for (int j = 0; j < 2; j++) {
            int jtg = w * 2 + j;
            bf16x8 bhi = *(const bf16x8*)(Wr1s +
                ((size_t)(0 * 4 + kc) * 8 + jtg) * 512 + lane * 8);
            bf16x8 blo = *(const bf16x8*)(Wr1s +
                ((size_t)(1 * 4 + kc) * 8 + jtg) * 512 + lane * 8);
#pragma unroll
            for (int m = 0; m < 2; m++) {
                acc[m][j] = __builtin_amdgcn_mfma_f32_16x16x32_bf16(
                    A[m][0], bhi, acc[m][j], 0, 0, 0);
                acc[m][j] = __builtin_amdgcn_mfma_f32_16x16x32_bf16(
                    A[m][0], blo, acc[m][j], 0, 0, 0);
                acc[m][j] = __builtin_amdgcn_mfma_f32_16x16x32_bf16(
                    A[m][1], bhi, acc[m][j], 0, 0, 0);
            }
        }
    }

    float part[2][4];
#pragma unroll
    for (int m = 0; m < 2; m++)
#pragma unroll
        for (int g = 0; g < 4; g++) part[m][g] = 0.f;
#pragma unroll
    for (int j = 0; j < 2; j++) {
        int col = (w * 2 + j) * 16 + r;
        float b1v = br1[col], w2v = Wr2[col];
#pragma unroll
        for (int m = 0; m < 2; m++)
#pragma unroll
            for (int g = 0; g < 4; g++)
                part[m][g] += fmaxf(acc[m][j][g] + b1v, 0.f) * w2v;
    }
#pragma unroll
    for (int mask = 1; mask < 16; mask <<= 1)
#pragma unroll
        for (int m = 0; m < 2; m++)
#pragma unroll
            for (int g = 0; g < 4; g++)
                part[m][g] += __shfl_xor(part[m][g], mask, 16);
    if (r == 0) {
#pragma unroll
        for (int m = 0; m < 2; m++)
#pragma unroll
            for (int g = 0; g < 4; g++)
                sRed[w][m * 16 + quad * 4 + g] = part[m][g];
    }
    __syncthreads();
    if (tid < 32) {
        int n = nb + tid;
        if (n < n_out)
            out[n] = sRed[0][tid] + sRed[1][tid] + sRed[2][tid] + sRed[3][tid]
                     + br2[0];
    }
}

// ---------------------------------------------------------------------------
extern "C" void kernel_launch(void* const* d_in, const int* in_sizes, int n_in,
                              void* d_out, int out_size, void* d_ws, size_t ws_size,
                              hipStream_t stream)
{
    const float* x      = (const float*)d_in[0];
    const int*   eidx   = (const int*)d_in[1];
    const int*   etype  = (const int*)d_in[2];
    const float* Win    = (const float*)d_in[4];
    const float* bin    = (const float*)d_in[5];
    const float* W1     = (const float*)d_in[6];   // (3,2,256,128)
    const float* b1     = (const float*)d_in[7];   // (3,2,128)
    const float* W2     = (const float*)d_in[8];   // (3,2,128,128)
    const float* b2     = (const float*)d_in[9];   // (3,2,128)
    const float* Wih    = (const float*)d_in[10];  // (3,128,384)
    const float* bih    = (const float*)d_in[11];  // (3,384)
    const float* Whh    = (const float*)d_in[12];  // (3,128,384)
    const float* bhh    = (const float*)d_in[13];  // (3,384)
    const float* Wr1    = (const float*)d_in[14];
    const float* br1    = (const float*)d_in[15];
    const float* Wr2    = (const float*)d_in[16];
    const float* br2    = (const float*)d_in[17];

    const int n_nodes = in_sizes[0] / FEAT;
    const int n_edges = in_sizes[1] / 2;
    const int L = 3;
    const size_t nh = (size_t)n_nodes * H;

    const int* src = eidx;
    const int* dst = eidx + n_edges;

    // workspace carve-up
    float*  h    = (float*)d_ws;                    // 25.6 MB
    float*  agg  = h + nh;                          // 25.6 MB
    __bf16* hb   = (__bf16*)(agg + nh);             // 12.8 MB
    __bf16* Wsw  = hb + nh;                         // WC_TOTAL bf16
    __bf16* Wg   = Wsw + WC_TOTAL;                  // 3*WG_PER_LAYER bf16
    __bf16* Wr1s = Wg + 3 * WG_PER_LAYER;           // WR_TOTAL bf16
    int* bucket  = (int*)(Wr1s + WR_TOTAL);         // n_edges
    int* cnt     = bucket + n_edges;                // 2*nn (also k_place cursors)
    int* offs    = cnt + 2 * n_nodes;               // 2*nn + 1
    int* bsum    = offs + 2 * n_nodes + 1;          // scan block sums (<=1024)
    // P/HA arrays (aligned): PT/PB bf16 [2][nn][H] (25.6 MB each),
    // HA f32 [2][nn][H] (51.2 MB)
    unsigned long long pa = (unsigned long long)(bsum + 2048);
    pa = (pa + 255ull) & ~255ull;
    __bf16* PT = (__bf16*)pa;
    __bf16* PB = PT + (size_t)2 * n_nodes * H;
    float*  HA = (float*)(PB + (size_t)2 * n_nodes * H);

    const int nscan = 2 * n_nodes;
    const int nb = (nscan + 1023) / 1024;

    // one mega-prep kernel: weight swizzles + cnt zero + input proj
    const long long prep_total = (long long)WC_TOTAL + 3 * WG_PER_LAYER
                               + WR_TOTAL + nscan + (long long)nh;
    k_prep<<<(int)((prep_total + 255) / 256), 256, 0, stream>>>(
        W1, W2, Wih, Whh, Wr1, x, Win, bin,
        Wsw, Wg, Wr1s, cnt, h, hb, n_nodes);

    const int eb = (n_edges + 255) / 256;
    k_hist <<<eb, 256, 0, stream>>>(etype, dst, cnt, n_edges, n_nodes);
    k_scan1<<<nb, 1024, 0, stream>>>(cnt, bsum, nscan);
    k_scan2<<<1, 128, 0, stream>>>(bsum, offs, nb, nscan);
    k_scan3<<<nb, 1024, 0, stream>>>(cnt, bsum, offs, nscan);
    k_place<<<eb, 256, 0, stream>>>(etype, dst, offs, cnt, bucket, n_edges, n_nodes);

    const dim3 npgrid((n_nodes + 63) / 64, 2);
    const int egrid = (2 * n_nodes + 7) / 8;
    const int agrid = (n_nodes + 63) / 64;
    for (int l = 0; l < L; l++) {
        k_nodeproj<<<npgrid, 256, 0, stream>>>(
            hb, Wsw + (size_t)l * 2 * 12 * 4096,
            b1 + (size_t)l * 2 * H, PT, PB, n_nodes);
        k_edge<<<egrid, 512, 0, stream>>>(
            PT, PB, bucket, offs, src, HA, n_nodes);
        k_aggmm<<<agrid, 256, 0, stream>>>(
            HA, offs, Wsw + (size_t)l * 2 * 12 * 4096,
            b2 + (size_t)l * 2 * H, agg, n_nodes);
        k_gru<<<(n_nodes + 31) / 32, 1024, 0, stream>>>(
            h, hb, agg,
            Wg + (size_t)l * WG_PER_LAYER,
            bih + (size_t)l * 384, bhh + (size_t)l * 384,
            n_nodes, (l == L - 1) ? 1 : 0);
    }

    k_readout<<<(out_size + 31) / 32, 256, 0, stream>>>(
        h, Wr1s, br1, Wr2, br2, (float*)d_out, out_size);
}

// Round 7
// 569.667 us; speedup vs baseline: 1.1896x; 1.1896x over previous
//
#include <hip/hip_runtime.h>
#include <math.h>

// ---------------------------------------------------------------------------
// TannerGNN. Round 22: k_edge MLP surgery + nodeproj type-merge.
// R21 showed k_edge (79us) is dependent-load-latency bound (20% HBM, 18%
// VALU, no MFMA/LDS): serial avg-4 loop chaining bucket[e]->src->PT row.
// R22: (1) k_place writes SRC VALUES into the sorted array (bucket's only
// consumer was k_edge) -> one less dependency level; (2) k_edge unrolls x4
// with independent chains -- 4 uniform index loads coalesce to one
// s_load_dwordx4, 4 PT-row loads in flight (MLP=4 ~= avg run length);
// accumulation stays strictly in edge order => k_edge math bitwise identical
// to R21 (absmax 0.03100586). (3) k_nodeproj handles both types per block
// (16-chunk pipeline): hb fragments loaded once, traffic halved; per-type
// chunk order unchanged. Everything else identical to R21.
// N_NODES=50000, N_EDGES=400000, H=128, L=3, T=2, FEAT=4, N_DATA=40000.
// ---------------------------------------------------------------------------

#define H 128
#define HS  136        // sIn row stride in bf16 (gru/readout)
#define EXS 132        // sEx row stride in f32 (2-way banks)
#define FEAT 4
#define WG_PER_LAYER 196608   // 2 mat * 2 split * 4 kc * 24 jtg * 64 lane * 8
#define WR_TOTAL 32768        // 2 split * 4 kc * 8 jtg * 64 lane * 8
#define WC_TOTAL 294912       // 6 lt * 12 chunk * 4096

typedef __bf16 bf16x8 __attribute__((ext_vector_type(8)));
typedef __bf16 bf16x4 __attribute__((ext_vector_type(4)));
typedef __bf16 bf16x2 __attribute__((ext_vector_type(2)));
typedef float  f32x4  __attribute__((ext_vector_type(4)));

// async global->LDS, 16B per lane; l must be the wave-uniform base
// (HW writes lane i at l + i*16), g is the per-lane global address.
__device__ __forceinline__ void gload_lds16(const void* g, void* l) {
    __builtin_amdgcn_global_load_lds(
        (const __attribute__((address_space(1))) void*)g,
        (__attribute__((address_space(3))) void*)l, 16, 0, 0);
}

// ---------------- mega-prep: weight swizzles + cnt zero + input proj -------
__global__ __launch_bounds__(256) void k_prep(
    const float* __restrict__ W1, const float* __restrict__ W2,
    const float* __restrict__ Wih, const float* __restrict__ Whh,
    const float* __restrict__ Wr1,
    const float* __restrict__ x, const float* __restrict__ Win,
    const float* __restrict__ bin,
    __bf16* __restrict__ Wsw, __bf16* __restrict__ Wg,
    __bf16* __restrict__ Wr1s, int* __restrict__ cnt,
    float* __restrict__ h, __bf16* __restrict__ hb,
    int n_nodes)
{
    const int N1 = WC_TOTAL;
    const int N2 = 3 * WG_PER_LAYER;
    const int N3 = WR_TOTAL;
    const int N4 = 2 * n_nodes;
    const long long N5 = (long long)n_nodes * H;
    long long gid = (long long)blockIdx.x * 256 + threadIdx.x;

    if (gid < N1) {
        int g = (int)gid;
        const int per_lt = 12 * 4096;
        int lt = g / per_lt, rem = g % per_lt;
        int chunk = rem >> 12;
        int within = rem & 4095;
        int ct = within >> 9;
        int lane = (within >> 3) & 63;
        int j = within & 7;
        int r = lane & 15, quad = lane >> 4;
        int n = ct * 16 + r;
        float v;
        if (chunk < 8) {
            int k = chunk * 32 + quad * 8 + j;
            v = W1[((size_t)lt * 256 + k) * 128 + n];
        } else {
            int k = (chunk - 8) * 32 + quad * 8 + j;
            v = W2[((size_t)lt * 128 + k) * 128 + n];
        }
        Wsw[g] = (__bf16)v;
        return;
    }
    gid -= N1;
    if (gid < N2) {
        int g = (int)gid;
        int layer = g / WG_PER_LAYER, rem = g % WG_PER_LAYER;
        int t = rem & 7;
        int lane = (rem >> 3) & 63;
        int jtg = (rem >> 9) % 24;
        int mk = rem / 12288;          // (mat*2+split)*4 + kc
        int kc = mk & 3;
        int msplit = mk >> 2;
        int mat = msplit >> 1, split = msplit & 1;
        int r = lane & 15, quad = lane >> 4;
        int k = kc * 32 + quad * 8 + t;
        int n = jtg * 16 + r;
        const float* W = (mat ? Whh : Wih) + (size_t)layer * 128 * 384;
        float v = W[(size_t)k * 384 + n];
        __bf16 hi = (__bf16)v;
        Wg[g] = split ? (__bf16)(v - (float)hi) : hi;
        return;
    }
    gid -= N2;
    if (gid < N3) {
        int g = (int)gid;
        int t = g & 7;
        int lane = (g >> 3) & 63;
        int jtg = (g >> 9) & 7;
        int kc = (g >> 12) & 3;
        int split = g >> 14;
        int r = lane & 15, quad = lane >> 4;
        int k = kc * 32 + quad * 8 + t;
        int n = jtg * 16 + r;
        float v = Wr1[(size_t)k * H + n];
        __bf16 hi = (__bf16)v;
        Wr1s[g] = split ? (__bf16)(v - (float)hi) : hi;
        return;
    }
    gid -= N3;
    if (gid < N4) {
        cnt[(int)gid] = 0;
        return;
    }
    gid -= N4;
    if (gid < N5) {
        int idx = (int)gid;
        int n = idx >> 7, j = idx & 127;
        float acc = bin[j];
#pragma unroll
        for (int f = 0; f < FEAT; f++)
            acc += x[n * FEAT + f] * Win[f * H + j];
        float v = fmaxf(acc, 0.f);
        h[idx] = v;
        hb[idx] = (__bf16)v;
    }
}

// ---------------- counting sort by key = type*nn + dst ---------------------
__global__ __launch_bounds__(256) void k_hist(
    const int* __restrict__ et, const int* __restrict__ dst,
    int* __restrict__ cnt, int n_edges, int nn)
{
    int i = blockIdx.x * 256 + threadIdx.x;
    if (i < n_edges) atomicAdd(&cnt[et[i] * nn + dst[i]], 1);
}

__global__ __launch_bounds__(1024) void k_scan1(
    const int* __restrict__ cnt, int* __restrict__ bsum, int n)
{
    int i = blockIdx.x * 1024 + threadIdx.x;
    int v = (i < n) ? cnt[i] : 0;
#pragma unroll
    for (int off = 32; off > 0; off >>= 1) v += __shfl_down(v, off, 64);
    __shared__ int ws[16];
    int lane = threadIdx.x & 63, w = threadIdx.x >> 6;
    if (lane == 0) ws[w] = v;
    __syncthreads();
    if (threadIdx.x < 16) {
        int x = ws[threadIdx.x];
#pragma unroll
        for (int off = 8; off > 0; off >>= 1) x += __shfl_down(x, off, 64);
        if (threadIdx.x == 0) bsum[blockIdx.x] = x;
    }
}

__global__ __launch_bounds__(128) void k_scan2(
    int* __restrict__ bsum, int* __restrict__ offs, int nb, int n)
{
    int lane = threadIdx.x & 63, w = threadIdx.x >> 6;
    int v = (threadIdx.x < nb) ? bsum[threadIdx.x] : 0;
    int orig = v;
#pragma unroll
    for (int off = 1; off < 64; off <<= 1) {
        int t = __shfl_up(v, off, 64);
        if (lane >= off) v += t;
    }
    __shared__ int w0sum;
    if (threadIdx.x == 63) w0sum = v;
    __syncthreads();
    int ex = v - orig + (w ? w0sum : 0);
    if (threadIdx.x < nb) bsum[threadIdx.x] = ex;
    if (threadIdx.x == nb - 1) offs[n] = ex + orig;
}

__global__ __launch_bounds__(1024) void k_scan3(
    const int* __restrict__ cnt, const int* __restrict__ bsum,
    int* __restrict__ offs, int n)
{
    int i = blockIdx.x * 1024 + threadIdx.x;
    int v = (i < n) ? cnt[i] : 0;
    int orig = v;
    int lane = threadIdx.x & 63, w = threadIdx.x >> 6;
#pragma unroll
    for (int off = 1; off < 64; off <<= 1) {
        int t = __shfl_up(v, off, 64);
        if (lane >= off) v += t;
    }
    __shared__ int ws[16];
    if (lane == 63) ws[w] = v;
    __syncthreads();
    if (threadIdx.x < 16) {
        int x = ws[threadIdx.x];
#pragma unroll
        for (int off = 1; off < 16; off <<= 1) {
            int t = __shfl_up(x, off, 64);
            if (lane >= off) x += t;
        }
        ws[threadIdx.x] = x;
    }
    __syncthreads();
    int wbase = w ? ws[w - 1] : 0;
    if (i < n) offs[i] = bsum[blockIdx.x] + wbase + v - orig;
}

// place: store SRC VALUE at the sorted position (k_edge is the only consumer)
__global__ __launch_bounds__(256) void k_place(
    const int* __restrict__ et, const int* __restrict__ dst,
    const int* __restrict__ srcv,
    const int* __restrict__ offs, int* __restrict__ cnt,
    int* __restrict__ bucket, int n_edges, int nn)
{
    int i = blockIdx.x * 256 + threadIdx.x;
    if (i < n_edges) {
        int key = et[i] * nn + dst[i];
        int p = atomicAdd(&cnt[key], -1) - 1;
        bucket[offs[key] + p] = srcv[i];
    }
}

// ---------------- per-node projections: PT = hb@W1top + b1, PB = hb@W1bot --
// Both types per block (16-chunk pipeline); hb fragments loaded ONCE.
// 64 nodes/block, 4 waves x 16 nodes. Outputs bf16.
__global__ __launch_bounds__(256, 4) void k_nodeproj(
    const __bf16* __restrict__ hb, const __bf16* __restrict__ Wsw,
    const float* __restrict__ b1l,
    __bf16* __restrict__ PT, __bf16* __restrict__ PB, int n_nodes)
{
    const int nb = blockIdx.x * 64;
    __shared__ __bf16 sW[2][4096];

    const int tid = threadIdx.x, lane = tid & 63, w = tid >> 6;  // w: 0..3
    const int r = lane & 15, quad = lane >> 4;

    // stage chunk 0 (type 0): two 4KB issues (256 thr x 16B)
    gload_lds16(Wsw + (size_t)tid * 8, (char*)&sW[0][0] + (size_t)w * 1024);
    gload_lds16(Wsw + 2048 + (size_t)tid * 8,
                (char*)&sW[0][0] + 4096 + (size_t)w * 1024);

    const int n = nb + w * 16 + r;
    const int nc = (n < n_nodes) ? n : (n_nodes - 1);
    const __bf16* ap = hb + (size_t)nc * H;
    bf16x8 bf[4];
#pragma unroll
    for (int kc = 0; kc < 4; kc++)
        bf[kc] = *(const bf16x8*)(ap + kc * 32 + quad * 8);

    f32x4 at[8], ab[8];
#pragma unroll
    for (int ct = 0; ct < 8; ct++) {
        at[ct] = (f32x4){0.f, 0.f, 0.f, 0.f};
        ab[ct] = (f32x4){0.f, 0.f, 0.f, 0.f};
    }

    // c = t*8 + chunk; chunks 0-3 of each type -> at (PT), 4-7 -> ab (PB)
#pragma unroll
    for (int c = 0; c < 16; c++) {
        __syncthreads();
        if (c < 15) {
            int t2 = (c + 1) >> 3, c2 = (c + 1) & 7;
            size_t off = ((size_t)t2 * 12 + c2) * 4096;
            gload_lds16(Wsw + off + (size_t)tid * 8,
                        (char*)&sW[(c + 1) & 1][0] + (size_t)w * 1024);
            gload_lds16(Wsw + off + 2048 + (size_t)tid * 8,
                        (char*)&sW[(c + 1) & 1][0] + 4096 + (size_t)w * 1024);
        }
        const __bf16* cw = &sW[c & 1][0];
        bf16x8 b = bf[c & 3];
        if (((c >> 2) & 1) == 0) {
#pragma unroll
            for (int ct = 0; ct < 8; ct++) {
                bf16x8 a = *(const bf16x8*)(cw + ct * 512 + lane * 8);
                at[ct] = __builtin_amdgcn_mfma_f32_16x16x32_bf16(a, b, at[ct], 0, 0, 0);
            }
        } else {
#pragma unroll
            for (int ct = 0; ct < 8; ct++) {
                bf16x8 a = *(const bf16x8*)(cw + ct * 512 + lane * 8);
                ab[ct] = __builtin_amdgcn_mfma_f32_16x16x32_bf16(a, b, ab[ct], 0, 0, 0);
            }
        }
        if ((c & 7) == 7) {
            const int t = c >> 3;
            if (n < n_nodes) {
                __bf16* pt = PT + ((size_t)t * n_nodes + n) * H;
                __bf16* pb = PB + ((size_t)t * n_nodes + n) * H;
                const float* b1 = b1l + t * H;
#pragma unroll
                for (int ct = 0; ct < 8; ct++) {
                    f32x4 bb4 = *(const f32x4*)(b1 + ct * 16 + quad * 4);
                    bf16x4 vt, vb;
#pragma unroll
                    for (int g4 = 0; g4 < 4; g4++) {
                        vt[g4] = (__bf16)(at[ct][g4] + bb4[g4]);  // b1 folded
                        vb[g4] = (__bf16)(ab[ct][g4]);
                    }
                    *(bf16x4*)(pt + ct * 16 + quad * 4) = vt;
                    *(bf16x4*)(pb + ct * 16 + quad * 4) = vb;
                }
            }
#pragma unroll
            for (int ct = 0; ct < 8; ct++) {
                at[ct] = (f32x4){0.f, 0.f, 0.f, 0.f};
                ab[ct] = (f32x4){0.f, 0.f, 0.f, 0.f};
            }
        }
    }
}

// ---------------- edge sum: HA[key] = sum relu(PT[src] + PB[dst]) ----------
// One wave per (type,dst) key; lane owns features 2*lane, 2*lane+1.
// bucket[] holds SRC VALUES in sorted order. Unrolled x4: the 4 uniform
// index loads coalesce (s_load_dwordx4), 4 PT-row loads in flight (MLP=4).
// Adds remain strictly in edge order -> bitwise identical to R21.
__global__ __launch_bounds__(512) void k_edge(
    const __bf16* __restrict__ PT, const __bf16* __restrict__ PB,
    const int* __restrict__ bucket, const int* __restrict__ offs,
    float* __restrict__ HA, int nn)
{
    const int key = blockIdx.x * 8 + (threadIdx.x >> 6);
    if (key >= 2 * nn) return;
    const int e0 = offs[key], e1 = offs[key + 1];
    if (e0 == e1) return;
    const int lane = threadIdx.x & 63;
    const size_t tbase = (key >= nn) ? (size_t)nn : 0;   // type row base

    bf16x2 pv = *(const bf16x2*)(PB + (size_t)key * H + 2 * lane);
    const float p0 = (float)pv[0], p1 = (float)pv[1];

    float a0 = 0.f, a1 = 0.f;
    int e = e0;
    for (; e + 4 <= e1; e += 4) {
        int s0 = bucket[e], s1 = bucket[e + 1];
        int s2 = bucket[e + 2], s3 = bucket[e + 3];
        bf16x2 t0 = *(const bf16x2*)(PT + (tbase + s0) * H + 2 * lane);
        bf16x2 t1 = *(const bf16x2*)(PT + (tbase + s1) * H + 2 * lane);
        bf16x2 t2 = *(const bf16x2*)(PT + (tbase + s2) * H + 2 * lane);
        bf16x2 t3 = *(const bf16x2*)(PT + (tbase + s3) * H + 2 * lane);
        a0 += fmaxf((float)t0[0] + p0, 0.f);
        a1 += fmaxf((float)t0[1] + p1, 0.f);
        a0 += fmaxf((float)t1[0] + p0, 0.f);
        a1 += fmaxf((float)t1[1] + p1, 0.f);
        a0 += fmaxf((float)t2[0] + p0, 0.f);
        a1 += fmaxf((float)t2[1] + p1, 0.f);
        a0 += fmaxf((float)t3[0] + p0, 0.f);
        a1 += fmaxf((float)t3[1] + p1, 0.f);
    }
    for (; e < e1; ++e) {
        int s = bucket[e];
        bf16x2 tv = *(const bf16x2*)(PT + (tbase + s) * H + 2 * lane);
        a0 += fmaxf((float)tv[0] + p0, 0.f);
        a1 += fmaxf((float)tv[1] + p1, 0.f);
    }
    float2 o; o.x = a0; o.y = a1;
    *(float2*)(HA + (size_t)key * H + 2 * lane) = o;
}

// ---------------- agg GEMM: agg = split(HA_t)@W2_t + c_t*b2_t summed -------
// 64 nodes/block, 4 waves x 16 nodes; A = Wsw W2 chunks (8..11 per type),
// B = hi/lo bf16 split of HA rows (count-gated). Plain stores to agg.
__global__ __launch_bounds__(256) void k_aggmm(
    const float* __restrict__ HA, const int* __restrict__ offs,
    const __bf16* __restrict__ Wsw, const float* __restrict__ b2l,
    float* __restrict__ agg, int nn)
{
    const int nb = blockIdx.x * 64;
    __shared__ __bf16 sW[2][4096];

    const int tid = threadIdx.x, lane = tid & 63, w = tid >> 6;  // w: 0..3
    const int r = lane & 15, quad = lane >> 4;

    // stage chunk 0 = (t=0, kc=0): W2_0 chunk 8 of type 0
    gload_lds16(Wsw + (size_t)8 * 4096 + (size_t)tid * 8,
                (char*)&sW[0][0] + (size_t)w * 1024);
    gload_lds16(Wsw + (size_t)8 * 4096 + 2048 + (size_t)tid * 8,
                (char*)&sW[0][0] + 4096 + (size_t)w * 1024);

    const int n = nb + w * 16 + r;
    const int nc = (n < nn) ? n : (nn - 1);
    const int c0 = offs[nc + 1] - offs[nc];
    const int c1 = offs[nn + nc + 1] - offs[nn + nc];

    // B frags (hi/lo) for both types, count-gated (garbage never enters)
    bf16x8 bhi[2][4], blo[2][4];
#pragma unroll
    for (int t = 0; t < 2; t++) {
        const float* ha = HA + ((size_t)t * nn + nc) * H;
        const int cT = t ? c1 : c0;
#pragma unroll
        for (int kc = 0; kc < 4; kc++) {
            f32x4 u0 = *(const f32x4*)(ha + kc * 32 + quad * 8);
            f32x4 u1 = *(const f32x4*)(ha + kc * 32 + quad * 8 + 4);
#pragma unroll
            for (int j = 0; j < 4; j++) {
                float v0 = cT ? u0[j] : 0.f;
                float v1 = cT ? u1[j] : 0.f;
                __bf16 h0 = (__bf16)v0, h1 = (__bf16)v1;
                bhi[t][kc][j] = h0;     blo[t][kc][j] = (__bf16)(v0 - (float)h0);
                bhi[t][kc][4 + j] = h1; blo[t][kc][4 + j] = (__bf16)(v1 - (float)h1);
            }
        }
    }

    f32x4 acc[8];
#pragma unroll
    for (int ct = 0; ct < 8; ct++) acc[ct] = (f32x4){0.f, 0.f, 0.f, 0.f};

    // 8 chunks: c = t*4 + kc; W2_t chunk = Wsw + (t*12 + 8 + kc)*4096
#pragma unroll
    for (int c = 0; c < 8; c++) {
        __syncthreads();
        if (c < 7) {
            int t2 = (c + 1) >> 2, k2 = (c + 1) & 3;
            size_t off = (size_t)(t2 * 12 + 8 + k2) * 4096;
            gload_lds16(Wsw + off + (size_t)tid * 8,
                        (char*)&sW[(c + 1) & 1][0] + (size_t)w * 1024);
            gload_lds16(Wsw + off + 2048 + (size_t)tid * 8,
                        (char*)&sW[(c + 1) & 1][0] + 4096 + (size_t)w * 1024);
        }
        const __bf16* cw = &sW[c & 1][0];
        const int t = c >> 2, kc = c & 3;
        bf16x8 bh = bhi[t][kc], bl = blo[t][kc];
#pragma unroll
        for (int ct = 0; ct < 8; ct++) {
            bf16x8 a = *(const bf16x8*)(cw + ct * 512 + lane * 8);
            acc[ct] = __builtin_amdgcn_mfma_f32_16x16x32_bf16(a, bh, acc[ct], 0, 0, 0);
            acc[ct] = __builtin_amdgcn_mfma_f32_16x16x32_bf16(a, bl, acc[ct], 0, 0, 0);
        }
    }

    if (n < nn) {
        float* ag = agg + (size_t)n * H;
        const float f0 = (float)c0, f1 = (float)c1;
#pragma unroll
        for (int ct = 0; ct < 8; ct++) {
            f32x4 b20 = *(const f32x4*)(b2l + ct * 16 + quad * 4);
            f32x4 b21 = *(const f32x4*)(b2l + H + ct * 16 + quad * 4);
            f32x4 ov;
#pragma unroll
            for (int g4 = 0; g4 < 4; g4++)
                ov[g4] = acc[ct][g4] + f0 * b20[g4] + f1 * b21[g4];
            *(f32x4*)(ag + ct * 16 + quad * 4) = ov;
        }
    }
}

// ---------------- GRU cell: split-precision MFMA, mat-specialized waves ----
// last=1 (final layer): skip dead hb write. (agg zeroing removed: k_aggmm
// plain-stores agg every layer.)
__global__ __launch_bounds__(1024, 4) void k_gru(
    float* __restrict__ h, __bf16* __restrict__ hb,
    const float* __restrict__ agg,
    const __bf16* __restrict__ Wg,
    const float* __restrict__ bih, const float* __restrict__ bhh,
    int n_nodes, int last)
{
    const int nb = blockIdx.x * 32;
    const int tid = threadIdx.x;

    // phase 1: sIn[4][32][HS] bf16 (34816 B); phase 2: sEx[3][32][EXS] f32
    __shared__ char sRaw[3 * 32 * EXS * 4];          // 50688 B
    __bf16 (*sIn)[32][HS] = (__bf16(*)[32][HS])sRaw;
    float* sEx = (float*)sRaw;

    {   // stage + split inputs: one float4 of agg + h per thread
        int e = tid >> 5, c4 = (tid & 31) * 4;
        int n = nb + e;
        float4 av = {0.f, 0.f, 0.f, 0.f}, hv = {0.f, 0.f, 0.f, 0.f};
        if (n < n_nodes) {
            av = *(const float4*)(agg + (size_t)n * H + c4);
            hv = *(const float4*)(h + (size_t)n * H + c4);
        }
        bf16x4 ahi, alo, hhi, hlo;
        float af[4] = {av.x, av.y, av.z, av.w};
        float hf[4] = {hv.x, hv.y, hv.z, hv.w};
#pragma unroll
        for (int c = 0; c < 4; c++) {
            __bf16 ah = (__bf16)af[c]; ahi[c] = ah; alo[c] = (__bf16)(af[c] - (float)ah);
            __bf16 hh = (__bf16)hf[c]; hhi[c] = hh; hlo[c] = (__bf16)(hf[c] - (float)hh);
        }
        *(bf16x4*)&sIn[0][e][c4] = ahi;
        *(bf16x4*)&sIn[1][e][c4] = alo;
        *(bf16x4*)&sIn[2][e][c4] = hhi;
        *(bf16x4*)&sIn[3][e][c4] = hlo;
    }
    __syncthreads();

    const int lane = tid & 63, w = tid >> 6;     // w: 0..15
    const int r = lane & 15, quad = lane >> 4;
    const int jt = w & 7;
    const int mat = w >> 3;

    f32x4 acc[2][3];                     // [m][gate]
#pragma unroll
    for (int m = 0; m < 2; m++)
#pragma unroll
        for (int g = 0; g < 3; g++)
            acc[m][g] = (f32x4){0.f, 0.f, 0.f, 0.f};

    bf16x8 B[2][6];                      // [buf][g*2+split]
#pragma unroll
    for (int g = 0; g < 3; g++)
#pragma unroll
    for (int sp = 0; sp < 2; sp++)
        B[0][g * 2 + sp] = *(const bf16x8*)(Wg +
            ((((size_t)(mat * 2 + sp) * 4 + 0) * 24 + (g * 8 + jt)) * 64 + lane) * 8);

#pragma unroll
    for (int kc = 0; kc < 4; kc++) {
        const int cur = kc & 1, nxt = cur ^ 1;
        if (kc < 3) {
#pragma unroll
            for (int g = 0; g < 3; g++)
#pragma unroll
            for (int sp = 0; sp < 2; sp++)
                B[nxt][g * 2 + sp] = *(const bf16x8*)(Wg +
                    ((((size_t)(mat * 2 + sp) * 4 + (kc + 1)) * 24 + (g * 8 + jt)) * 64 + lane) * 8);
        }
        bf16x8 A[2][2];
#pragma unroll
        for (int m = 0; m < 2; m++)
#pragma unroll
            for (int s = 0; s < 2; s++)
                A[m][s] = *(const bf16x8*)&sIn[mat * 2 + s][m * 16 + r][kc * 32 + quad * 8];
#pragma unroll
        for (int g = 0; g < 3; g++) {
            bf16x8 bhi = B[cur][g * 2 + 0];
            bf16x8 blo = B[cur][g * 2 + 1];
#pragma unroll
            for (int m = 0; m < 2; m++) {
                acc[m][g] = __builtin_amdgcn_mfma_f32_16x16x32_bf16(
                    A[m][0], bhi, acc[m][g], 0, 0, 0);
                acc[m][g] = __builtin_amdgcn_mfma_f32_16x16x32_bf16(
                    A[m][0], blo, acc[m][g], 0, 0, 0);
                acc[m][g] = __builtin_amdgcn_mfma_f32_16x16x32_bf16(
                    A[m][1], bhi, acc[m][g], 0, 0, 0);
            }
        }
    }

    __syncthreads();   // all sIn reads done before sEx overwrites

    const int jcol = jt * 16 + r;
    if (mat == 1) {    // publish recurrent-gate accs
#pragma unroll
        for (int m = 0; m < 2; m++)
#pragma unroll
        for (int g = 0; g < 3; g++)
#pragma unroll
        for (int g4 = 0; g4 < 4; g4++) {
            int e = m * 16 + quad * 4 + g4;
            sEx[(g * 32 + e) * EXS + jcol] = acc[m][g][g4];
        }
    }
    __syncthreads();

    if (mat == 0) {    // gate epilogue
        float br_ = bih[jcol], bz_ = bih[128 + jcol], bn_ = bih[256 + jcol];
        float cr = bhh[jcol], cz = bhh[128 + jcol], cn = bhh[256 + jcol];
#pragma unroll
        for (int m = 0; m < 2; m++)
#pragma unroll
        for (int g4 = 0; g4 < 4; g4++) {
            int e = m * 16 + quad * 4 + g4;
            int n = nb + e;
            if (n < n_nodes) {
                float ir = acc[m][0][g4], iz = acc[m][1][g4], in_ = acc[m][2][g4];
                float hr = sEx[(0 * 32 + e) * EXS + jcol];
                float hz = sEx[(1 * 32 + e) * EXS + jcol];
                float hn = sEx[(2 * 32 + e) * EXS + jcol];
                float hold = h[(size_t)n * H + jcol];
                float rr = 1.f / (1.f + expf(-(ir + br_ + hr + cr)));
                float zz = 1.f / (1.f + expf(-(iz + bz_ + hz + cz)));
                float nv = tanhf(in_ + bn_ + rr * (hn + cn));
                float out = (1.f - zz) * nv + zz * hold;
                h[(size_t)n * H + jcol] = out;
                if (!last) hb[(size_t)n * H + jcol] = (__bf16)out;
            }
        }
    }
}

// ---------------- readout: split-precision MFMA ----------------------------
__global__ __launch_bounds__(256, 4) void k_readout(
    const float* __restrict__ h, const __bf16* __restrict__ Wr1s,
    const float* __restrict__ br1, const float* __restrict__ Wr2,
    const float* __restrict__ br2, float* __restrict__ out, int n_out)
{
    const int nb = blockIdx.x * 32;
    const int tid = threadIdx.x;
    __shared__ __bf16 sIn[2][32][HS];   // h hi/lo (17.4 KB)
    __shared__ float sRed[4][32];

#pragma unroll
    for (int v = 0; v < 4; v++) {
        int idx = tid + 256 * v;            // float4 id, 1024 total
        int e = idx >> 5, c4 = (idx & 31) * 4;
        int n = nb + e;
        float4 hv = {0.f, 0.f, 0.f, 0.f};
        if (n < n_out)
            hv = *(const float4*)(h + (size_t)n * H + c4);
        float hf[4] = {hv.x, hv.y, hv.z, hv.w};
        bf16x4 hhi, hlo;
#pragma unroll
        for (int c = 0; c < 4; c++) {
            __bf16 hh = (__bf16)hf[c];
            hhi[c] = hh; hlo[c] = (__bf16)(hf[c] - (float)hh);
        }
        *(bf16x4*)&sIn[0][e][c4] = hhi;
        *(bf16x4*)&sIn[1][e][c4] = hlo;
    }
    __syncthreads();

    const int lane = tid & 63, w = tid >> 6;
    const int r = lane & 15, quad = lane >> 4;

    f32x4 acc[2][2];                 // [m][j]
#pragma unroll
    for (int m = 0; m < 2; m++)
#pragma unroll
        for (int j = 0; j < 2; j++)
            acc[m][j] = (f32x4){0.f, 0.f, 0.f, 0.f};

#pragma unroll
    for (int kc = 0; kc < 4; kc++) {
        bf16x8 A[2][2];
#pragma unroll
        for (int m = 0; m < 2; m++)
#pragma unroll
            for (int s = 0; s < 2; s++)
                A[m][s] = *(const bf16x8*)&sIn[s][m * 16 + r][kc * 32 + quad * 8];
#pragma unroll
        for (int j = 0; j < 2; j++) {
            int jtg = w * 2 + j;
            bf16x8 bhi = *(const bf16x8*)(Wr1s +
                ((size_t)(0 * 4 + kc) * 8 + jtg) * 512 + lane * 8);
            bf16x8 blo = *(const bf16x8*)(Wr1s +
                ((size_t)(1 * 4 + kc) * 8 + jtg) * 512 + lane * 8);
#pragma unroll
            for (int m = 0; m < 2; m++) {
                acc[m][j] = __builtin_amdgcn_mfma_f32_16x16x32_bf16(
                    A[m][0], bhi, acc[m][j], 0, 0, 0);
                acc[m][j] = __builtin_amdgcn_mfma_f32_16x16x32_bf16(
                    A[m][0], blo, acc[m][j], 0, 0, 0);
                acc[m][j] = __builtin_amdgcn_mfma_f32_16x16x32_bf16(
                    A[m][1], bhi, acc[m][j], 0, 0, 0);
            }
        }
    }

    float part[2][4];
#pragma unroll
    for (int m = 0; m < 2; m++)
#pragma unroll
        for (int g = 0; g < 4; g++) part[m][g] = 0.f;
#pragma unroll
    for (int j = 0; j < 2; j++) {
        int col = (w * 2 + j) * 16 + r;
        float b1v = br1[col], w2v = Wr2[col];
#pragma unroll
        for (int m = 0; m < 2; m++)
#pragma unroll
            for (int g = 0; g < 4; g++)
                part[m][g] += fmaxf(acc[m][j][g] + b1v, 0.f) * w2v;
    }
#pragma unroll
    for (int mask = 1; mask < 16; mask <<= 1)
#pragma unroll
        for (int m = 0; m < 2; m++)
#pragma unroll
            for (int g = 0; g < 4; g++)
                part[m][g] += __shfl_xor(part[m][g], mask, 16);
    if (r == 0) {
#pragma unroll
        for (int m = 0; m < 2; m++)
#pragma unroll
            for (int g = 0; g < 4; g++)
                sRed[w][m * 16 + quad * 4 + g] = part[m][g];
    }
    __syncthreads();
    if (tid < 32) {
        int n = nb + tid;
        if (n < n_out)
            out[n] = sRed[0][tid] + sRed[1][tid] + sRed[2][tid] + sRed[3][tid]
                     + br2[0];
    }
}

// ---------------------------------------------------------------------------
extern "C" void kernel_launch(void* const* d_in, const int* in_sizes, int n_in,
                              void* d_out, int out_size, void* d_ws, size_t ws_size,
                              hipStream_t stream)
{
    const float* x      = (const float*)d_in[0];
    const int*   eidx   = (const int*)d_in[1];
    const int*   etype  = (const int*)d_in[2];
    const float* Win    = (const float*)d_in[4];
    const float* bin    = (const float*)d_in[5];
    const float* W1     = (const float*)d_in[6];   // (3,2,256,128)
    const float* b1     = (const float*)d_in[7];   // (3,2,128)
    const float* W2     = (const float*)d_in[8];   // (3,2,128,128)
    const float* b2     = (const float*)d_in[9];   // (3,2,128)
    const float* Wih    = (const float*)d_in[10];  // (3,128,384)
    const float* bih    = (const float*)d_in[11];  // (3,384)
    const float* Whh    = (const float*)d_in[12];  // (3,128,384)
    const float* bhh    = (const float*)d_in[13];  // (3,384)
    const float* Wr1    = (const float*)d_in[14];
    const float* br1    = (const float*)d_in[15];
    const float* Wr2    = (const float*)d_in[16];
    const float* br2    = (const float*)d_in[17];

    const int n_nodes = in_sizes[0] / FEAT;
    const int n_edges = in_sizes[1] / 2;
    const int L = 3;
    const size_t nh = (size_t)n_nodes * H;

    const int* src = eidx;
    const int* dst = eidx + n_edges;

    // workspace carve-up
    float*  h    = (float*)d_ws;                    // 25.6 MB
    float*  agg  = h + nh;                          // 25.6 MB
    __bf16* hb   = (__bf16*)(agg + nh);             // 12.8 MB
    __bf16* Wsw  = hb + nh;                         // WC_TOTAL bf16
    __bf16* Wg   = Wsw + WC_TOTAL;                  // 3*WG_PER_LAYER bf16
    __bf16* Wr1s = Wg + 3 * WG_PER_LAYER;           // WR_TOTAL bf16
    int* bucket  = (int*)(Wr1s + WR_TOTAL);         // n_edges (src values)
    int* cnt     = bucket + n_edges;                // 2*nn (also k_place cursors)
    int* offs    = cnt + 2 * n_nodes;               // 2*nn + 1
    int* bsum    = offs + 2 * n_nodes + 1;          // scan block sums (<=1024)
    // P/HA arrays (aligned): PT/PB bf16 [2][nn][H] (25.6 MB each),
    // HA f32 [2][nn][H] (51.2 MB)
    unsigned long long pa = (unsigned long long)(bsum + 2048);
    pa = (pa + 255ull) & ~255ull;
    __bf16* PT = (__bf16*)pa;
    __bf16* PB = PT + (size_t)2 * n_nodes * H;
    float*  HA = (float*)(PB + (size_t)2 * n_nodes * H);

    const int nscan = 2 * n_nodes;
    const int nb = (nscan + 1023) / 1024;

    // one mega-prep kernel: weight swizzles + cnt zero + input proj
    const long long prep_total = (long long)WC_TOTAL + 3 * WG_PER_LAYER
                               + WR_TOTAL + nscan + (long long)nh;
    k_prep<<<(int)((prep_total + 255) / 256), 256, 0, stream>>>(
        W1, W2, Wih, Whh, Wr1, x, Win, bin,
        Wsw, Wg, Wr1s, cnt, h, hb, n_nodes);

    const int eb = (n_edges + 255) / 256;
    k_hist <<<eb, 256, 0, stream>>>(etype, dst, cnt, n_edges, n_nodes);
    k_scan1<<<nb, 1024, 0, stream>>>(cnt, bsum, nscan);
    k_scan2<<<1, 128, 0, stream>>>(bsum, offs, nb, nscan);
    k_scan3<<<nb, 1024, 0, stream>>>(cnt, bsum, offs, nscan);
    k_place<<<eb, 256, 0, stream>>>(etype, dst, src, offs, cnt, bucket,
                                    n_edges, n_nodes);

    const int npgrid = (n_nodes + 63) / 64;
    const int egrid = (2 * n_nodes + 7) / 8;
    const int agrid = (n_nodes + 63) / 64;
    for (int l = 0; l < L; l++) {
        k_nodeproj<<<npgrid, 256, 0, stream>>>(
            hb, Wsw + (size_t)l * 2 * 12 * 4096,
            b1 + (size_t)l * 2 * H, PT, PB, n_nodes);
        k_edge<<<egrid, 512, 0, stream>>>(
            PT, PB, bucket, offs, HA, n_nodes);
        k_aggmm<<<agrid, 256, 0, stream>>>(
            HA, offs, Wsw + (size_t)l * 2 * 12 * 4096,
            b2 + (size_t)l * 2 * H, agg, n_nodes);
        k_gru<<<(n_nodes + 31) / 32, 1024, 0, stream>>>(
            h, hb, agg,
            Wg + (size_t)l * WG_PER_LAYER,
            bih + (size_t)l * 384, bhh + (size_t)l * 384,
            n_nodes, (l == L - 1) ? 1 : 0);
    }

    k_readout<<<(out_size + 31) / 32, 256, 0, stream>>>(
        h, Wr1s, br1, Wr2, br2, (float*)d_out, out_size);
}

// Round 8
// 564.172 us; speedup vs baseline: 1.2012x; 1.0097x over previous
//
#include <hip/hip_runtime.h>
#include <math.h>

// ---------------------------------------------------------------------------
// TannerGNN. Round 23: k_gru epilogue surgery. R22 profile: k_gru 54.5us x3
// is the top kernel, VALUBusy 50% / MfmaUtil 21% / HBM 15% -> VALU-bound.
// Cause: epilogue transcendentals ran on HALF the block (mat==0 waves only,
// 8 outputs/thread, libm expf/tanhf ~40 ops each) while mat==1 idled.
// Fix 1: symmetric split -- mat1 publishes its m=0 accs (sEx rows e<16),
// mat0 publishes its m=1 accs (rows e>=16); every wave then finishes its own
// m-half: 4 outputs/thread on ALL waves (transcendental wall /2). Same sEx
// planes; acc indexing kept compile-time via wave-uniform branches.
// Fix 2: native activations: sigmoid = rcp(1+exp2(-x*log2e)), tanh =
// 1-2*rcp(exp2(2x*log2e)+1) (v_exp_f32/v_rcp_f32, ~2ulp; correct saturation).
// Gate-sum operand order unchanged -> pre-activation values bitwise same;
// absmax may drift ulps around 0.031. Everything else identical to R22.
// N_NODES=50000, N_EDGES=400000, H=128, L=3, T=2, FEAT=4, N_DATA=40000.
// ---------------------------------------------------------------------------

#define H 128
#define HS  136        // sIn row stride in bf16 (gru/readout)
#define EXS 132        // sEx row stride in f32 (2-way banks)
#define FEAT 4
#define WG_PER_LAYER 196608   // 2 mat * 2 split * 4 kc * 24 jtg * 64 lane * 8
#define WR_TOTAL 32768        // 2 split * 4 kc * 8 jtg * 64 lane * 8
#define WC_TOTAL 294912       // 6 lt * 12 chunk * 4096

typedef __bf16 bf16x8 __attribute__((ext_vector_type(8)));
typedef __bf16 bf16x4 __attribute__((ext_vector_type(4)));
typedef __bf16 bf16x2 __attribute__((ext_vector_type(2)));
typedef float  f32x4  __attribute__((ext_vector_type(4)));

// async global->LDS, 16B per lane; l must be the wave-uniform base
// (HW writes lane i at l + i*16), g is the per-lane global address.
__device__ __forceinline__ void gload_lds16(const void* g, void* l) {
    __builtin_amdgcn_global_load_lds(
        (const __attribute__((address_space(1))) void*)g,
        (__attribute__((address_space(3))) void*)l, 16, 0, 0);
}

// native-activation helpers: v_exp_f32 (2^x) + v_rcp_f32, ~2 ulp,
// correct saturation (exp2->inf => sig->0/1, tanh->+-1).
__device__ __forceinline__ float fsigmoid(float x) {
    return __builtin_amdgcn_rcpf(
        1.f + __builtin_amdgcn_exp2f(-1.442695040888963f * x));
}
__device__ __forceinline__ float ftanh(float x) {
    float t = __builtin_amdgcn_exp2f(2.885390081777926f * x);
    return 1.f - 2.f * __builtin_amdgcn_rcpf(t + 1.f);
}

// ---------------- mega-prep: weight swizzles + cnt zero + input proj -------
__global__ __launch_bounds__(256) void k_prep(
    const float* __restrict__ W1, const float* __restrict__ W2,
    const float* __restrict__ Wih, const float* __restrict__ Whh,
    const float* __restrict__ Wr1,
    const float* __restrict__ x, const float* __restrict__ Win,
    const float* __restrict__ bin,
    __bf16* __restrict__ Wsw, __bf16* __restrict__ Wg,
    __bf16* __restrict__ Wr1s, int* __restrict__ cnt,
    float* __restrict__ h, __bf16* __restrict__ hb,
    int n_nodes)
{
    const int N1 = WC_TOTAL;
    const int N2 = 3 * WG_PER_LAYER;
    const int N3 = WR_TOTAL;
    const int N4 = 2 * n_nodes;
    const long long N5 = (long long)n_nodes * H;
    long long gid = (long long)blockIdx.x * 256 + threadIdx.x;

    if (gid < N1) {
        int g = (int)gid;
        const int per_lt = 12 * 4096;
        int lt = g / per_lt, rem = g % per_lt;
        int chunk = rem >> 12;
        int within = rem & 4095;
        int ct = within >> 9;
        int lane = (within >> 3) & 63;
        int j = within & 7;
        int r = lane & 15, quad = lane >> 4;
        int n = ct * 16 + r;
        float v;
        if (chunk < 8) {
            int k = chunk * 32 + quad * 8 + j;
            v = W1[((size_t)lt * 256 + k) * 128 + n];
        } else {
            int k = (chunk - 8) * 32 + quad * 8 + j;
            v = W2[((size_t)lt * 128 + k) * 128 + n];
        }
        Wsw[g] = (__bf16)v;
        return;
    }
    gid -= N1;
    if (gid < N2) {
        int g = (int)gid;
        int layer = g / WG_PER_LAYER, rem = g % WG_PER_LAYER;
        int t = rem & 7;
        int lane = (rem >> 3) & 63;
        int jtg = (rem >> 9) % 24;
        int mk = rem / 12288;          // (mat*2+split)*4 + kc
        int kc = mk & 3;
        int msplit = mk >> 2;
        int mat = msplit >> 1, split = msplit & 1;
        int r = lane & 15, quad = lane >> 4;
        int k = kc * 32 + quad * 8 + t;
        int n = jtg * 16 + r;
        const float* W = (mat ? Whh : Wih) + (size_t)layer * 128 * 384;
        float v = W[(size_t)k * 384 + n];
        __bf16 hi = (__bf16)v;
        Wg[g] = split ? (__bf16)(v - (float)hi) : hi;
        return;
    }
    gid -= N2;
    if (gid < N3) {
        int g = (int)gid;
        int t = g & 7;
        int lane = (g >> 3) & 63;
        int jtg = (g >> 9) & 7;
        int kc = (g >> 12) & 3;
        int split = g >> 14;
        int r = lane & 15, quad = lane >> 4;
        int k = kc * 32 + quad * 8 + t;
        int n = jtg * 16 + r;
        float v = Wr1[(size_t)k * H + n];
        __bf16 hi = (__bf16)v;
        Wr1s[g] = split ? (__bf16)(v - (float)hi) : hi;
        return;
    }
    gid -= N3;
    if (gid < N4) {
        cnt[(int)gid] = 0;
        return;
    }
    gid -= N4;
    if (gid < N5) {
        int idx = (int)gid;
        int n = idx >> 7, j = idx & 127;
        float acc = bin[j];
#pragma unroll
        for (int f = 0; f < FEAT; f++)
            acc += x[n * FEAT + f] * Win[f * H + j];
        float v = fmaxf(acc, 0.f);
        h[idx] = v;
        hb[idx] = (__bf16)v;
    }
}

// ---------------- counting sort by key = type*nn + dst ---------------------
__global__ __launch_bounds__(256) void k_hist(
    const int* __restrict__ et, const int* __restrict__ dst,
    int* __restrict__ cnt, int n_edges, int nn)
{
    int i = blockIdx.x * 256 + threadIdx.x;
    if (i < n_edges) atomicAdd(&cnt[et[i] * nn + dst[i]], 1);
}

__global__ __launch_bounds__(1024) void k_scan1(
    const int* __restrict__ cnt, int* __restrict__ bsum, int n)
{
    int i = blockIdx.x * 1024 + threadIdx.x;
    int v = (i < n) ? cnt[i] : 0;
#pragma unroll
    for (int off = 32; off > 0; off >>= 1) v += __shfl_down(v, off, 64);
    __shared__ int ws[16];
    int lane = threadIdx.x & 63, w = threadIdx.x >> 6;
    if (lane == 0) ws[w] = v;
    __syncthreads();
    if (threadIdx.x < 16) {
        int x = ws[threadIdx.x];
#pragma unroll
        for (int off = 8; off > 0; off >>= 1) x += __shfl_down(x, off, 64);
        if (threadIdx.x == 0) bsum[blockIdx.x] = x;
    }
}

__global__ __launch_bounds__(128) void k_scan2(
    int* __restrict__ bsum, int* __restrict__ offs, int nb, int n)
{
    int lane = threadIdx.x & 63, w = threadIdx.x >> 6;
    int v = (threadIdx.x < nb) ? bsum[threadIdx.x] : 0;
    int orig = v;
#pragma unroll
    for (int off = 1; off < 64; off <<= 1) {
        int t = __shfl_up(v, off, 64);
        if (lane >= off) v += t;
    }
    __shared__ int w0sum;
    if (threadIdx.x == 63) w0sum = v;
    __syncthreads();
    int ex = v - orig + (w ? w0sum : 0);
    if (threadIdx.x < nb) bsum[threadIdx.x] = ex;
    if (threadIdx.x == nb - 1) offs[n] = ex + orig;
}

__global__ __launch_bounds__(1024) void k_scan3(
    const int* __restrict__ cnt, const int* __restrict__ bsum,
    int* __restrict__ offs, int n)
{
    int i = blockIdx.x * 1024 + threadIdx.x;
    int v = (i < n) ? cnt[i] : 0;
    int orig = v;
    int lane = threadIdx.x & 63, w = threadIdx.x >> 6;
#pragma unroll
    for (int off = 1; off < 64; off <<= 1) {
        int t = __shfl_up(v, off, 64);
        if (lane >= off) v += t;
    }
    __shared__ int ws[16];
    if (lane == 63) ws[w] = v;
    __syncthreads();
    if (threadIdx.x < 16) {
        int x = ws[threadIdx.x];
#pragma unroll
        for (int off = 1; off < 16; off <<= 1) {
            int t = __shfl_up(x, off, 64);
            if (lane >= off) x += t;
        }
        ws[threadIdx.x] = x;
    }
    __syncthreads();
    int wbase = w ? ws[w - 1] : 0;
    if (i < n) offs[i] = bsum[blockIdx.x] + wbase + v - orig;
}

// place: store SRC VALUE at the sorted position (k_edge is the only consumer)
__global__ __launch_bounds__(256) void k_place(
    const int* __restrict__ et, const int* __restrict__ dst,
    const int* __restrict__ srcv,
    const int* __restrict__ offs, int* __restrict__ cnt,
    int* __restrict__ bucket, int n_edges, int nn)
{
    int i = blockIdx.x * 256 + threadIdx.x;
    if (i < n_edges) {
        int key = et[i] * nn + dst[i];
        int p = atomicAdd(&cnt[key], -1) - 1;
        bucket[offs[key] + p] = srcv[i];
    }
}

// ---------------- per-node projections: PT = hb@W1top + b1, PB = hb@W1bot --
// Both types per block (16-chunk pipeline); hb fragments loaded ONCE.
// 64 nodes/block, 4 waves x 16 nodes. Outputs bf16.
__global__ __launch_bounds__(256, 4) void k_nodeproj(
    const __bf16* __restrict__ hb, const __bf16* __restrict__ Wsw,
    const float* __restrict__ b1l,
    __bf16* __restrict__ PT, __bf16* __restrict__ PB, int n_nodes)
{
    const int nb = blockIdx.x * 64;
    __shared__ __bf16 sW[2][4096];

    const int tid = threadIdx.x, lane = tid & 63, w = tid >> 6;  // w: 0..3
    const int r = lane & 15, quad = lane >> 4;

    // stage chunk 0 (type 0): two 4KB issues (256 thr x 16B)
    gload_lds16(Wsw + (size_t)tid * 8, (char*)&sW[0][0] + (size_t)w * 1024);
    gload_lds16(Wsw + 2048 + (size_t)tid * 8,
                (char*)&sW[0][0] + 4096 + (size_t)w * 1024);

    const int n = nb + w * 16 + r;
    const int nc = (n < n_nodes) ? n : (n_nodes - 1);
    const __bf16* ap = hb + (size_t)nc * H;
    bf16x8 bf[4];
#pragma unroll
    for (int kc = 0; kc < 4; kc++)
        bf[kc] = *(const bf16x8*)(ap + kc * 32 + quad * 8);

    f32x4 at[8], ab[8];
#pragma unroll
    for (int ct = 0; ct < 8; ct++) {
        at[ct] = (f32x4){0.f, 0.f, 0.f, 0.f};
        ab[ct] = (f32x4){0.f, 0.f, 0.f, 0.f};
    }

    // c = t*8 + chunk; chunks 0-3 of each type -> at (PT), 4-7 -> ab (PB)
#pragma unroll
    for (int c = 0; c < 16; c++) {
        __syncthreads();
        if (c < 15) {
            int t2 = (c + 1) >> 3, c2 = (c + 1) & 7;
            size_t off = ((size_t)t2 * 12 + c2) * 4096;
            gload_lds16(Wsw + off + (size_t)tid * 8,
                        (char*)&sW[(c + 1) & 1][0] + (size_t)w * 1024);
            gload_lds16(Wsw + off + 2048 + (size_t)tid * 8,
                        (char*)&sW[(c + 1) & 1][0] + 4096 + (size_t)w * 1024);
        }
        const __bf16* cw = &sW[c & 1][0];
        bf16x8 b = bf[c & 3];
        if (((c >> 2) & 1) == 0) {
#pragma unroll
            for (int ct = 0; ct < 8; ct++) {
                bf16x8 a = *(const bf16x8*)(cw + ct * 512 + lane * 8);
                at[ct] = __builtin_amdgcn_mfma_f32_16x16x32_bf16(a, b, at[ct], 0, 0, 0);
            }
        } else {
#pragma unroll
            for (int ct = 0; ct < 8; ct++) {
                bf16x8 a = *(const bf16x8*)(cw + ct * 512 + lane * 8);
                ab[ct] = __builtin_amdgcn_mfma_f32_16x16x32_bf16(a, b, ab[ct], 0, 0, 0);
            }
        }
        if ((c & 7) == 7) {
            const int t = c >> 3;
            if (n < n_nodes) {
                __bf16* pt = PT + ((size_t)t * n_nodes + n) * H;
                __bf16* pb = PB + ((size_t)t * n_nodes + n) * H;
                const float* b1 = b1l + t * H;
#pragma unroll
                for (int ct = 0; ct < 8; ct++) {
                    f32x4 bb4 = *(const f32x4*)(b1 + ct * 16 + quad * 4);
                    bf16x4 vt, vb;
#pragma unroll
                    for (int g4 = 0; g4 < 4; g4++) {
                        vt[g4] = (__bf16)(at[ct][g4] + bb4[g4]);  // b1 folded
                        vb[g4] = (__bf16)(ab[ct][g4]);
                    }
                    *(bf16x4*)(pt + ct * 16 + quad * 4) = vt;
                    *(bf16x4*)(pb + ct * 16 + quad * 4) = vb;
                }
            }
#pragma unroll
            for (int ct = 0; ct < 8; ct++) {
                at[ct] = (f32x4){0.f, 0.f, 0.f, 0.f};
                ab[ct] = (f32x4){0.f, 0.f, 0.f, 0.f};
            }
        }
    }
}

// ---------------- edge sum: HA[key] = sum relu(PT[src] + PB[dst]) ----------
// One wave per (type,dst) key; lane owns features 2*lane, 2*lane+1.
// bucket[] holds SRC VALUES in sorted order. Unrolled x4: the 4 uniform
// index loads coalesce (s_load_dwordx4), 4 PT-row loads in flight (MLP=4).
// Adds remain strictly in edge order.
__global__ __launch_bounds__(512) void k_edge(
    const __bf16* __restrict__ PT, const __bf16* __restrict__ PB,
    const int* __restrict__ bucket, const int* __restrict__ offs,
    float* __restrict__ HA, int nn)
{
    const int key = blockIdx.x * 8 + (threadIdx.x >> 6);
    if (key >= 2 * nn) return;
    const int e0 = offs[key], e1 = offs[key + 1];
    if (e0 == e1) return;
    const int lane = threadIdx.x & 63;
    const size_t tbase = (key >= nn) ? (size_t)nn : 0;   // type row base

    bf16x2 pv = *(const bf16x2*)(PB + (size_t)key * H + 2 * lane);
    const float p0 = (float)pv[0], p1 = (float)pv[1];

    float a0 = 0.f, a1 = 0.f;
    int e = e0;
    for (; e + 4 <= e1; e += 4) {
        int s0 = bucket[e], s1 = bucket[e + 1];
        int s2 = bucket[e + 2], s3 = bucket[e + 3];
        bf16x2 t0 = *(const bf16x2*)(PT + (tbase + s0) * H + 2 * lane);
        bf16x2 t1 = *(const bf16x2*)(PT + (tbase + s1) * H + 2 * lane);
        bf16x2 t2 = *(const bf16x2*)(PT + (tbase + s2) * H + 2 * lane);
        bf16x2 t3 = *(const bf16x2*)(PT + (tbase + s3) * H + 2 * lane);
        a0 += fmaxf((float)t0[0] + p0, 0.f);
        a1 += fmaxf((float)t0[1] + p1, 0.f);
        a0 += fmaxf((float)t1[0] + p0, 0.f);
        a1 += fmaxf((float)t1[1] + p1, 0.f);
        a0 += fmaxf((float)t2[0] + p0, 0.f);
        a1 += fmaxf((float)t2[1] + p1, 0.f);
        a0 += fmaxf((float)t3[0] + p0, 0.f);
        a1 += fmaxf((float)t3[1] + p1, 0.f);
    }
    for (; e < e1; ++e) {
        int s = bucket[e];
        bf16x2 tv = *(const bf16x2*)(PT + (tbase + s) * H + 2 * lane);
        a0 += fmaxf((float)tv[0] + p0, 0.f);
        a1 += fmaxf((float)tv[1] + p1, 0.f);
    }
    float2 o; o.x = a0; o.y = a1;
    *(float2*)(HA + (size_t)key * H + 2 * lane) = o;
}

// ---------------- agg GEMM: agg = split(HA_t)@W2_t + c_t*b2_t summed -------
// 64 nodes/block, 4 waves x 16 nodes; A = Wsw W2 chunks (8..11 per type),
// B = hi/lo bf16 split of HA rows (count-gated). Plain stores to agg.
__global__ __launch_bounds__(256) void k_aggmm(
    const float* __restrict__ HA, const int* __restrict__ offs,
    const __bf16* __restrict__ Wsw, const float* __restrict__ b2l,
    float* __restrict__ agg, int nn)
{
    const int nb = blockIdx.x * 64;
    __shared__ __bf16 sW[2][4096];

    const int tid = threadIdx.x, lane = tid & 63, w = tid >> 6;  // w: 0..3
    const int r = lane & 15, quad = lane >> 4;

    // stage chunk 0 = (t=0, kc=0): W2_0 chunk 8 of type 0
    gload_lds16(Wsw + (size_t)8 * 4096 + (size_t)tid * 8,
                (char*)&sW[0][0] + (size_t)w * 1024);
    gload_lds16(Wsw + (size_t)8 * 4096 + 2048 + (size_t)tid * 8,
                (char*)&sW[0][0] + 4096 + (size_t)w * 1024);

    const int n = nb + w * 16 + r;
    const int nc = (n < nn) ? n : (nn - 1);
    const int c0 = offs[nc + 1] - offs[nc];
    const int c1 = offs[nn + nc + 1] - offs[nn + nc];

    // B frags (hi/lo) for both types, count-gated (garbage never enters)
    bf16x8 bhi[2][4], blo[2][4];
#pragma unroll
    for (int t = 0; t < 2; t++) {
        const float* ha = HA + ((size_t)t * nn + nc) * H;
        const int cT = t ? c1 : c0;
#pragma unroll
        for (int kc = 0; kc < 4; kc++) {
            f32x4 u0 = *(const f32x4*)(ha + kc * 32 + quad * 8);
            f32x4 u1 = *(const f32x4*)(ha + kc * 32 + quad * 8 + 4);
#pragma unroll
            for (int j = 0; j < 4; j++) {
                float v0 = cT ? u0[j] : 0.f;
                float v1 = cT ? u1[j] : 0.f;
                __bf16 h0 = (__bf16)v0, h1 = (__bf16)v1;
                bhi[t][kc][j] = h0;     blo[t][kc][j] = (__bf16)(v0 - (float)h0);
                bhi[t][kc][4 + j] = h1; blo[t][kc][4 + j] = (__bf16)(v1 - (float)h1);
            }
        }
    }

    f32x4 acc[8];
#pragma unroll
    for (int ct = 0; ct < 8; ct++) acc[ct] = (f32x4){0.f, 0.f, 0.f, 0.f};

    // 8 chunks: c = t*4 + kc; W2_t chunk = Wsw + (t*12 + 8 + kc)*4096
#pragma unroll
    for (int c = 0; c < 8; c++) {
        __syncthreads();
        if (c < 7) {
            int t2 = (c + 1) >> 2, k2 = (c + 1) & 3;
            size_t off = (size_t)(t2 * 12 + 8 + k2) * 4096;
            gload_lds16(Wsw + off + (size_t)tid * 8,
                        (char*)&sW[(c + 1) & 1][0] + (size_t)w * 1024);
            gload_lds16(Wsw + off + 2048 + (size_t)tid * 8,
                        (char*)&sW[(c + 1) & 1][0] + 4096 + (size_t)w * 1024);
        }
        const __bf16* cw = &sW[c & 1][0];
        const int t = c >> 2, kc = c & 3;
        bf16x8 bh = bhi[t][kc], bl = blo[t][kc];
#pragma unroll
        for (int ct = 0; ct < 8; ct++) {
            bf16x8 a = *(const bf16x8*)(cw + ct * 512 + lane * 8);
            acc[ct] = __builtin_amdgcn_mfma_f32_16x16x32_bf16(a, bh, acc[ct], 0, 0, 0);
            acc[ct] = __builtin_amdgcn_mfma_f32_16x16x32_bf16(a, bl, acc[ct], 0, 0, 0);
        }
    }

    if (n < nn) {
        float* ag = agg + (size_t)n * H;
        const float f0 = (float)c0, f1 = (float)c1;
#pragma unroll
        for (int ct = 0; ct < 8; ct++) {
            f32x4 b20 = *(const f32x4*)(b2l + ct * 16 + quad * 4);
            f32x4 b21 = *(const f32x4*)(b2l + H + ct * 16 + quad * 4);
            f32x4 ov;
#pragma unroll
            for (int g4 = 0; g4 < 4; g4++)
                ov[g4] = acc[ct][g4] + f0 * b20[g4] + f1 * b21[g4];
            *(f32x4*)(ag + ct * 16 + quad * 4) = ov;
        }
    }
}

// ---------------- GRU cell: split-precision MFMA, mat-specialized waves ----
// R23: symmetric epilogue. mat1 publishes its m=0 accs (sEx rows e<16),
// mat0 publishes its m=1 accs (rows e>=16); every wave finishes its own
// m-half (4 outputs/thread). Native sigmoid/tanh (v_exp/v_rcp).
// last=1 (final layer): skip dead hb write.
__global__ __launch_bounds__(1024, 4) void k_gru(
    float* __restrict__ h, __bf16* __restrict__ hb,
    const float* __restrict__ agg,
    const __bf16* __restrict__ Wg,
    const float* __restrict__ bih, const float* __restrict__ bhh,
    int n_nodes, int last)
{
    const int nb = blockIdx.x * 32;
    const int tid = threadIdx.x;

    // phase 1: sIn[4][32][HS] bf16 (34816 B); phase 2: sEx[3][32][EXS] f32
    __shared__ char sRaw[3 * 32 * EXS * 4];          // 50688 B
    __bf16 (*sIn)[32][HS] = (__bf16(*)[32][HS])sRaw;
    float* sEx = (float*)sRaw;

    {   // stage + split inputs: one float4 of agg + h per thread
        int e = tid >> 5, c4 = (tid & 31) * 4;
        int n = nb + e;
        float4 av = {0.f, 0.f, 0.f, 0.f}, hv = {0.f, 0.f, 0.f, 0.f};
        if (n < n_nodes) {
            av = *(const float4*)(agg + (size_t)n * H + c4);
            hv = *(const float4*)(h + (size_t)n * H + c4);
        }
        bf16x4 ahi, alo, hhi, hlo;
        float af[4] = {av.x, av.y, av.z, av.w};
        float hf[4] = {hv.x, hv.y, hv.z, hv.w};
#pragma unroll
        for (int c = 0; c < 4; c++) {
            __bf16 ah = (__bf16)af[c]; ahi[c] = ah; alo[c] = (__bf16)(af[c] - (float)ah);
            __bf16 hh = (__bf16)hf[c]; hhi[c] = hh; hlo[c] = (__bf16)(hf[c] - (float)hh);
        }
        *(bf16x4*)&sIn[0][e][c4] = ahi;
        *(bf16x4*)&sIn[1][e][c4] = alo;
        *(bf16x4*)&sIn[2][e][c4] = hhi;
        *(bf16x4*)&sIn[3][e][c4] = hlo;
    }
    __syncthreads();

    const int lane = tid & 63, w = tid >> 6;     // w: 0..15
    const int r = lane & 15, quad = lane >> 4;
    const int jt = w & 7;
    const int mat = w >> 3;

    f32x4 acc[2][3];                     // [m][gate]
#pragma unroll
    for (int m = 0; m < 2; m++)
#pragma unroll
        for (int g = 0; g < 3; g++)
            acc[m][g] = (f32x4){0.f, 0.f, 0.f, 0.f};

    bf16x8 B[2][6];                      // [buf][g*2+split]
#pragma unroll
    for (int g = 0; g < 3; g++)
#pragma unroll
    for (int sp = 0; sp < 2; sp++)
        B[0][g * 2 + sp] = *(const bf16x8*)(Wg +
            ((((size_t)(mat * 2 + sp) * 4 + 0) * 24 + (g * 8 + jt)) * 64 + lane) * 8);

#pragma unroll
    for (int kc = 0; kc < 4; kc++) {
        const int cur = kc & 1, nxt = cur ^ 1;
        if (kc < 3) {
#pragma unroll
            for (int g = 0; g < 3; g++)
#pragma unroll
            for (int sp = 0; sp < 2; sp++)
                B[nxt][g * 2 + sp] = *(const bf16x8*)(Wg +
                    ((((size_t)(mat * 2 + sp) * 4 + (kc + 1)) * 24 + (g * 8 + jt)) * 64 + lane) * 8);
        }
        bf16x8 A[2][2];
#pragma unroll
        for (int m = 0; m < 2; m++)
#pragma unroll
            for (int s = 0; s < 2; s++)
                A[m][s] = *(const bf16x8*)&sIn[mat * 2 + s][m * 16 + r][kc * 32 + quad * 8];
#pragma unroll
        for (int g = 0; g < 3; g++) {
            bf16x8 bhi = B[cur][g * 2 + 0];
            bf16x8 blo = B[cur][g * 2 + 1];
#pragma unroll
            for (int m = 0; m < 2; m++) {
                acc[m][g] = __builtin_amdgcn_mfma_f32_16x16x32_bf16(
                    A[m][0], bhi, acc[m][g], 0, 0, 0);
                acc[m][g] = __builtin_amdgcn_mfma_f32_16x16x32_bf16(
                    A[m][0], blo, acc[m][g], 0, 0, 0);
                acc[m][g] = __builtin_amdgcn_mfma_f32_16x16x32_bf16(
                    A[m][1], bhi, acc[m][g], 0, 0, 0);
            }
        }
    }

    __syncthreads();   // all sIn reads done before sEx overwrites

    const int jcol = jt * 16 + r;
    // publish the half the partner wave will finish (compile-time acc index):
    // mat0 publishes its m=1 accs -> rows e>=16 (i-gates for mat1's half);
    // mat1 publishes its m=0 accs -> rows e<16  (h-gates for mat0's half).
    if (mat == 0) {
#pragma unroll
        for (int g = 0; g < 3; g++)
#pragma unroll
        for (int g4 = 0; g4 < 4; g4++) {
            int e = 16 + quad * 4 + g4;
            sEx[(g * 32 + e) * EXS + jcol] = acc[1][g][g4];
        }
    } else {
#pragma unroll
        for (int g = 0; g < 3; g++)
#pragma unroll
        for (int g4 = 0; g4 < 4; g4++) {
            int e = quad * 4 + g4;
            sEx[(g * 32 + e) * EXS + jcol] = acc[0][g][g4];
        }
    }
    __syncthreads();

    {   // every wave finishes its own m-half: 4 outputs/thread
        float br_ = bih[jcol], bz_ = bih[128 + jcol], bn_ = bih[256 + jcol];
        float cr = bhh[jcol], cz = bhh[128 + jcol], cn = bhh[256 + jcol];
#pragma unroll
        for (int g4 = 0; g4 < 4; g4++) {
            int e = mat * 16 + quad * 4 + g4;
            int n = nb + e;
            if (n < n_nodes) {
                float s0 = sEx[(0 * 32 + e) * EXS + jcol];
                float s1 = sEx[(1 * 32 + e) * EXS + jcol];
                float s2 = sEx[(2 * 32 + e) * EXS + jcol];
                float ir, iz, in_, hr, hz, hn;
                if (mat == 0) {           // own = i-gates (m=0), sEx = h-gates
                    ir = acc[0][0][g4]; iz = acc[0][1][g4]; in_ = acc[0][2][g4];
                    hr = s0; hz = s1; hn = s2;
                } else {                  // own = h-gates (m=1), sEx = i-gates
                    hr = acc[1][0][g4]; hz = acc[1][1][g4]; hn = acc[1][2][g4];
                    ir = s0; iz = s1; in_ = s2;
                }
                float hold = h[(size_t)n * H + jcol];
                float rr = fsigmoid(ir + br_ + hr + cr);
                float zz = fsigmoid(iz + bz_ + hz + cz);
                float nv = ftanh(in_ + bn_ + rr * (hn + cn));
                float out = (1.f - zz) * nv + zz * hold;
                h[(size_t)n * H + jcol] = out;
                if (!last) hb[(size_t)n * H + jcol] = (__bf16)out;
            }
        }
    }
}

// ---------------- readout: split-precision MFMA ----------------------------
__global__ __launch_bounds__(256, 4) void k_readout(
    const float* __restrict__ h, const __bf16* __restrict__ Wr1s,
    const float* __restrict__ br1, const float* __restrict__ Wr2,
    const float* __restrict__ br2, float* __restrict__ out, int n_out)
{
    const int nb = blockIdx.x * 32;
    const int tid = threadIdx.x;
    __shared__ __bf16 sIn[2][32][HS];   // h hi/lo (17.4 KB)
    __shared__ float sRed[4][32];

#pragma unroll
    for (int v = 0; v < 4; v++) {
        int idx = tid + 256 * v;            // float4 id, 1024 total
        int e = idx >> 5, c4 = (idx & 31) * 4;
        int n = nb + e;
        float4 hv = {0.f, 0.f, 0.f, 0.f};
        if (n < n_out)
            hv = *(const float4*)(h + (size_t)n * H + c4);
        float hf[4] = {hv.x, hv.y, hv.z, hv.w};
        bf16x4 hhi, hlo;
#pragma unroll
        for (int c = 0; c < 4; c++) {
            __bf16 hh = (__bf16)hf[c];
            hhi[c] = hh; hlo[c] = (__bf16)(hf[c] - (float)hh);
        }
        *(bf16x4*)&sIn[0][e][c4] = hhi;
        *(bf16x4*)&sIn[1][e][c4] = hlo;
    }
    __syncthreads();

    const int lane = tid & 63, w = tid >> 6;
    const int r = lane & 15, quad = lane >> 4;

    f32x4 acc[2][2];                 // [m][j]
#pragma unroll
    for (int m = 0; m < 2; m++)
#pragma unroll
        for (int j = 0; j < 2; j++)
            acc[m][j] = (f32x4){0.f, 0.f, 0.f, 0.f};

#pragma unroll
    for (int kc = 0; kc < 4; kc++) {
        bf16x8 A[2][2];
#pragma unroll
        for (int m = 0; m < 2; m++)
#pragma unroll
            for (int s = 0; s < 2; s++)
                A[m][s] = *(const bf16x8*)&sIn[s][m * 16 + r][kc * 32 + quad * 8];
#pragma unroll
        for (int j = 0; j < 2; j++) {
            int jtg = w * 2 + j;
            bf16x8 bhi = *(const bf16x8*)(Wr1s +
                ((size_t)(0 * 4 + kc) * 8 + jtg) * 512 + lane * 8);
            bf16x8 blo = *(const bf16x8*)(Wr1s +
                ((size_t)(1 * 4 + kc) * 8 + jtg) * 512 + lane * 8);
#pragma unroll
            for (int m = 0; m < 2; m++) {
                acc[m][j] = __builtin_amdgcn_mfma_f32_16x16x32_bf16(
                    A[m][0], bhi, acc[m][j], 0, 0, 0);
                acc[m][j] = __builtin_amdgcn_mfma_f32_16x16x32_bf16(
                    A[m][0], blo, acc[m][j], 0, 0, 0);
                acc[m][j] = __builtin_amdgcn_mfma_f32_16x16x32_bf16(
                    A[m][1], bhi, acc[m][j], 0, 0, 0);
            }
        }
    }

    float part[2][4];
#pragma unroll
    for (int m = 0; m < 2; m++)
#pragma unroll
        for (int g = 0; g < 4; g++) part[m][g] = 0.f;
#pragma unroll
    for (int j = 0; j < 2; j++) {
        int col = (w * 2 + j) * 16 + r;
        float b1v = br1[col], w2v = Wr2[col];
#pragma unroll
        for (int m = 0; m < 2; m++)
#pragma unroll
            for (int g = 0; g < 4; g++)
                part[m][g] += fmaxf(acc[m][j][g] + b1v, 0.f) * w2v;
    }
#pragma unroll
    for (int mask = 1; mask < 16; mask <<= 1)
#pragma unroll
        for (int m = 0; m < 2; m++)
#pragma unroll
            for (int g = 0; g < 4; g++)
                part[m][g] += __shfl_xor(part[m][g], mask, 16);
    if (r == 0) {
#pragma unroll
        for (int m = 0; m < 2; m++)
#pragma unroll
            for (int g = 0; g < 4; g++)
                sRed[w][m * 16 + quad * 4 + g] = part[m][g];
    }
    __syncthreads();
    if (tid < 32) {
        int n = nb + tid;
        if (n < n_out)
            out[n] = sRed[0][tid] + sRed[1][tid] + sRed[2][tid] + sRed[3][tid]
                     + br2[0];
    }
}

// ---------------------------------------------------------------------------
extern "C" void kernel_launch(void* const* d_in, const int* in_sizes, int n_in,
                              void* d_out, int out_size, void* d_ws, size_t ws_size,
                              hipStream_t stream)
{
    const float* x      = (const float*)d_in[0];
    const int*   eidx   = (const int*)d_in[1];
    const int*   etype  = (const int*)d_in[2];
    const float* Win    = (const float*)d_in[4];
    const float* bin    = (const float*)d_in[5];
    const float* W1     = (const float*)d_in[6];   // (3,2,256,128)
    const float* b1     = (const float*)d_in[7];   // (3,2,128)
    const float* W2     = (const float*)d_in[8];   // (3,2,128,128)
    const float* b2     = (const float*)d_in[9];   // (3,2,128)
    const float* Wih    = (const float*)d_in[10];  // (3,128,384)
    const float* bih    = (const float*)d_in[11];  // (3,384)
    const float* Whh    = (const float*)d_in[12];  // (3,128,384)
    const float* bhh    = (const float*)d_in[13];  // (3,384)
    const float* Wr1    = (const float*)d_in[14];
    const float* br1    = (const float*)d_in[15];
    const float* Wr2    = (const float*)d_in[16];
    const float* br2    = (const float*)d_in[17];

    const int n_nodes = in_sizes[0] / FEAT;
    const int n_edges = in_sizes[1] / 2;
    const int L = 3;
    const size_t nh = (size_t)n_nodes * H;

    const int* src = eidx;
    const int* dst = eidx + n_edges;

    // workspace carve-up
    float*  h    = (float*)d_ws;                    // 25.6 MB
    float*  agg  = h + nh;                          // 25.6 MB
    __bf16* hb   = (__bf16*)(agg + nh);             // 12.8 MB
    __bf16* Wsw  = hb + nh;                         // WC_TOTAL bf16
    __bf16* Wg   = Wsw + WC_TOTAL;                  // 3*WG_PER_LAYER bf16
    __bf16* Wr1s = Wg + 3 * WG_PER_LAYER;           // WR_TOTAL bf16
    int* bucket  = (int*)(Wr1s + WR_TOTAL);         // n_edges (src values)
    int* cnt     = bucket + n_edges;                // 2*nn (also k_place cursors)
    int* offs    = cnt + 2 * n_nodes;               // 2*nn + 1
    int* bsum    = offs + 2 * n_nodes + 1;          // scan block sums (<=1024)
    // P/HA arrays (aligned): PT/PB bf16 [2][nn][H] (25.6 MB each),
    // HA f32 [2][nn][H] (51.2 MB)
    unsigned long long pa = (unsigned long long)(bsum + 2048);
    pa = (pa + 255ull) & ~255ull;
    __bf16* PT = (__bf16*)pa;
    __bf16* PB = PT + (size_t)2 * n_nodes * H;
    float*  HA = (float*)(PB + (size_t)2 * n_nodes * H);

    const int nscan = 2 * n_nodes;
    const int nb = (nscan + 1023) / 1024;

    // one mega-prep kernel: weight swizzles + cnt zero + input proj
    const long long prep_total = (long long)WC_TOTAL + 3 * WG_PER_LAYER
                               + WR_TOTAL + nscan + (long long)nh;
    k_prep<<<(int)((prep_total + 255) / 256), 256, 0, stream>>>(
        W1, W2, Wih, Whh, Wr1, x, Win, bin,
        Wsw, Wg, Wr1s, cnt, h, hb, n_nodes);

    const int eb = (n_edges + 255) / 256;
    k_hist <<<eb, 256, 0, stream>>>(etype, dst, cnt, n_edges, n_nodes);
    k_scan1<<<nb, 1024, 0, stream>>>(cnt, bsum, nscan);
    k_scan2<<<1, 128, 0, stream>>>(bsum, offs, nb, nscan);
    k_scan3<<<nb, 1024, 0, stream>>>(cnt, bsum, offs, nscan);
    k_place<<<eb, 256, 0, stream>>>(etype, dst, src, offs, cnt, bucket,
                                    n_edges, n_nodes);

    const int npgrid = (n_nodes + 63) / 64;
    const int egrid = (2 * n_nodes + 7) / 8;
    const int agrid = (n_nodes + 63) / 64;
    for (int l = 0; l < L; l++) {
        k_nodeproj<<<npgrid, 256, 0, stream>>>(
            hb, Wsw + (size_t)l * 2 * 12 * 4096,
            b1 + (size_t)l * 2 * H, PT, PB, n_nodes);
        k_edge<<<egrid, 512, 0, stream>>>(
            PT, PB, bucket, offs, HA, n_nodes);
        k_aggmm<<<agrid, 256, 0, stream>>>(
            HA, offs, Wsw + (size_t)l * 2 * 12 * 4096,
            b2 + (size_t)l * 2 * H, agg, n_nodes);
        k_gru<<<(n_nodes + 31) / 32, 1024, 0, stream>>>(
            h, hb, agg,
            Wg + (size_t)l * WG_PER_LAYER,
            bih + (size_t)l * 384, bhh + (size_t)l * 384,
            n_nodes, (l == L - 1) ? 1 : 0);
    }

    k_readout<<<(out_size + 31) / 32, 256, 0, stream>>>(
        h, Wr1s, br1, Wr2, br2, (float*)d_out, out_size);
}